// Round 1
// baseline (9322.279 us; speedup 1.0000x reference)
//
#include <hip/hip_runtime.h>

#define TPB 256

// ---------------- degree / norm ----------------

__global__ void k_deg_init(float* deg, int n) {
    int i = blockIdx.x * blockDim.x + threadIdx.x;
    if (i < n) deg[i] = 1.0f;  // self-loop
}

__global__ void k_deg_accum(const int* __restrict__ dst, float* deg, int E) {
    int e = blockIdx.x * blockDim.x + threadIdx.x;
    if (e < E) atomicAdd(&deg[dst[e]], 1.0f);
}

__global__ void k_rsqrt_inplace(float* d, int n) {
    int i = blockIdx.x * blockDim.x + threadIdx.x;
    if (i < n) d[i] = rsqrtf(d[i]);
}

__global__ void k_norm(const int* __restrict__ src, const int* __restrict__ dst,
                       const float* __restrict__ dis, float* __restrict__ nrm, int E) {
    int e = blockIdx.x * blockDim.x + threadIdx.x;
    if (e < E) nrm[e] = dis[src[e]] * dis[dst[e]];
}

// ---------------- dense matmul h[N,FI] @ W[FI,FO] ----------------

template <int FI, int FO>
__global__ __launch_bounds__(TPB) void k_matmul(const float* __restrict__ h,
                                                const float* __restrict__ W,
                                                float* __restrict__ out, int n) {
    __shared__ float sW[FI * FO];
    for (int i = threadIdx.x; i < FI * FO; i += blockDim.x) sW[i] = W[i];
    __syncthreads();
    int idx = blockIdx.x * blockDim.x + threadIdx.x;
    int node = idx / FO;
    int j = idx % FO;
    if (node >= n) return;
    const float* row = h + (size_t)node * FI;
    float acc = 0.f;
#pragma unroll
    for (int k = 0; k < FI; ++k) acc = fmaf(row[k], sW[k * FO + j], acc);
    out[(size_t)node * FO + j] = acc;
}

// ---------------- GCN aggregation ----------------

// hA[n] = hB[n] * dis[n]^2   (self-loop contribution; also inits accumulator)
template <int FO>
__global__ void k_selfloop(const float* __restrict__ hB, const float* __restrict__ dis,
                           float* __restrict__ hA, int n) {
    int idx = blockIdx.x * blockDim.x + threadIdx.x;
    if (idx >= n * FO) return;
    int node = idx / FO;
    float d = dis[node];
    hA[idx] = hB[idx] * d * d;
}

// scatter: hA[dst] += hB[src] * nrm[e], 4 channels per thread
template <int FO>
__global__ void k_edge_agg(const int* __restrict__ src, const int* __restrict__ dst,
                           const float* __restrict__ nrm, const float* __restrict__ hB,
                           float* __restrict__ hA, int E) {
    constexpr int G = FO / 4;
    int idx = blockIdx.x * blockDim.x + threadIdx.x;
    int e = idx / G;
    int g = idx % G;
    if (e >= E) return;
    int s = src[e], d = dst[e];
    float w = nrm[e];
    const float4 v = *(const float4*)(hB + (size_t)s * FO + g * 4);
    float* o = hA + (size_t)d * FO + g * 4;
    atomicAdd(o + 0, v.x * w);
    atomicAdd(o + 1, v.y * w);
    atomicAdd(o + 2, v.z * w);
    atomicAdd(o + 3, v.w * w);
}

// ---------------- BatchNorm (training-mode batch stats) ----------------

template <int FO>
__global__ __launch_bounds__(TPB) void k_bn_stats(const float* __restrict__ h,
                                                  float* __restrict__ stats, int n) {
    int c = threadIdx.x % FO;
    const int rows_per = TPB / FO;
    int r0 = blockIdx.x * rows_per + threadIdx.x / FO;
    int rstride = gridDim.x * rows_per;
    float s = 0.f, s2 = 0.f;
    for (int r = r0; r < n; r += rstride) {
        float v = h[(size_t)r * FO + c];
        s += v;
        s2 += v * v;
    }
    __shared__ float ls[TPB], ls2[TPB];
    ls[threadIdx.x] = s;
    ls2[threadIdx.x] = s2;
    __syncthreads();
    if (threadIdx.x < FO) {
        float a = 0.f, b = 0.f;
        for (int t = threadIdx.x; t < TPB; t += FO) { a += ls[t]; b += ls2[t]; }
        atomicAdd(&stats[c], a);
        atomicAdd(&stats[FO + c], b);
    }
}

template <int FO, bool RELU>
__global__ void k_bn_apply(float* __restrict__ h, const float* __restrict__ stats,
                           const float* __restrict__ g, const float* __restrict__ be, int n) {
    int idx = blockIdx.x * blockDim.x + threadIdx.x;
    if (idx >= n * FO) return;
    int c = idx % FO;
    float inv_n = 1.0f / (float)n;
    float mu = stats[c] * inv_n;
    float var = stats[FO + c] * inv_n - mu * mu;
    float sc = g[c] * rsqrtf(var + 1e-5f);
    float v = (h[idx] - mu) * sc + be[c];
    h[idx] = RELU ? fmaxf(v, 0.f) : v;
}

// ---------------- segment multi-aggregation ----------------

__global__ void k_seg_off(const int* __restrict__ bidx, int n, int* __restrict__ seg_off, int S) {
    int s = blockIdx.x * blockDim.x + threadIdx.x;
    if (s > S) return;
    int lo = 0, hi = n;
    while (lo < hi) {
        int mid = (lo + hi) >> 1;
        if (bidx[mid] < s) lo = mid + 1; else hi = mid;
    }
    seg_off[s] = lo;
}

// one block (256 thr) per segment; C=64; writes aggin[s][0:256] = mean|min|max|std
__global__ __launch_bounds__(TPB) void k_seg_reduce(const float* __restrict__ h,
                                                    const int* __restrict__ seg_off,
                                                    float* __restrict__ aggin) {
    int s = blockIdx.x;
    int start = seg_off[s], end = seg_off[s + 1];
    int c = threadIdx.x & 63;
    int r0 = start + (threadIdx.x >> 6);
    float sm = 0.f, sm2 = 0.f, mn = INFINITY, mx = -INFINITY;
    for (int r = r0; r < end; r += 4) {
        float v = h[(size_t)r * 64 + c];
        sm += v;
        sm2 += v * v;
        mn = fminf(mn, v);
        mx = fmaxf(mx, v);
    }
    __shared__ float s_sm[TPB], s_sm2[TPB], s_mn[TPB], s_mx[TPB];
    s_sm[threadIdx.x] = sm;
    s_sm2[threadIdx.x] = sm2;
    s_mn[threadIdx.x] = mn;
    s_mx[threadIdx.x] = mx;
    __syncthreads();
    if (threadIdx.x < 64) {
        for (int t = threadIdx.x + 64; t < TPB; t += 64) {
            sm += s_sm[t];
            sm2 += s_sm2[t];
            mn = fminf(mn, s_mn[t]);
            mx = fmaxf(mx, s_mx[t]);
        }
        int count = end - start;
        float cnt = (float)(count > 0 ? count : 1);
        float mean = sm / cnt;
        float var = sm2 / cnt - mean * mean;
        if (var < 0.f) var = 0.f;
        float sd = sqrtf(var + 1e-5f);
        if (count <= 0) { mn = 0.f; mx = 0.f; }
        aggin[s * 256 + c] = mean;
        aggin[s * 256 + 64 + c] = mn;
        aggin[s * 256 + 128 + c] = mx;
        aggin[s * 256 + 192 + c] = sd;
    }
}

// proj[s][j] = aggin[s][:] @ Wp[:,j] + bp[j]; 64 threads per block, block per segment
__global__ __launch_bounds__(64) void k_proj(const float* __restrict__ aggin,
                                             const float* __restrict__ Wp,
                                             const float* __restrict__ bp,
                                             float* __restrict__ proj) {
    __shared__ float sA[256];
    int s = blockIdx.x;
    int j = threadIdx.x;
    for (int k = j; k < 256; k += 64) sA[k] = aggin[s * 256 + k];
    __syncthreads();
    float acc = bp[j];
#pragma unroll 8
    for (int k = 0; k < 256; ++k) acc = fmaf(sA[k], Wp[k * 64 + j], acc);
    proj[s * 64 + j] = acc;
}

// out[b][c][jj][ii] = (ii*14+jj < num_sp[b]) ? proj[offs[b] + ii*14+jj][c] : 0
__global__ void k_pack(const float* __restrict__ proj, const int* __restrict__ num_sp,
                       float* __restrict__ out, int B, int S) {
    int idx = blockIdx.x * blockDim.x + threadIdx.x;
    int total = B * 64 * 196;
    if (idx >= total) return;
    int ii = idx % 14;
    int jj = (idx / 14) % 14;
    int c = (idx / 196) % 64;
    int b = idx / (196 * 64);
    int p = ii * 14 + jj;
    int off = 0;
    for (int k = 0; k < b; ++k) off += num_sp[k];
    float v = 0.f;
    if (p < num_sp[b]) {
        int s = off + p;
        if (s > S - 1) s = S - 1;
        v = proj[s * 64 + c];
    }
    out[idx] = v;
}

// ---------------- launch ----------------

extern "C" void kernel_launch(void* const* d_in, const int* in_sizes, int n_in,
                              void* d_out, int out_size, void* d_ws, size_t ws_size,
                              hipStream_t stream) {
    const float* x = (const float*)d_in[0];
    const int* ei = (const int*)d_in[1];
    const int* bidx = (const int*)d_in[2];
    const int* num_sp = (const int*)d_in[3];
    const float* Wl[5], * Gl[5], * BEl[5];
    for (int i = 0; i < 5; ++i) {
        Wl[i] = (const float*)d_in[4 + 4 * i];
        // bias d_in[5+4*i] skipped: per-channel constant cancels in training-mode BN
        Gl[i] = (const float*)d_in[6 + 4 * i];
        BEl[i] = (const float*)d_in[7 + 4 * i];
    }
    const float* Wp = (const float*)d_in[24];
    const float* bp = (const float*)d_in[25];

    const int n_nodes = in_sizes[0] / 24;
    const int n_edges = in_sizes[1] / 2;
    const int B = in_sizes[3];
    const int S = 1200;  // B * NUM_SP
    const int* src = ei;
    const int* dst = ei + n_edges;

    // workspace carve (all chunks 256B-aligned)
    char* w = (char*)d_ws;
    float* hA = (float*)w;      w += (size_t)n_nodes * 64 * 4;
    float* hB = (float*)w;      w += (size_t)n_nodes * 64 * 4;
    float* dis = (float*)w;     w += (size_t)n_nodes * 4;
    float* nrm = (float*)w;     w += (size_t)n_edges * 4;
    float* stats = (float*)w;   w += 1024;
    int* seg_off = (int*)w;     w += 8192;
    float* aggin = (float*)w;   w += (size_t)S * 256 * 4;
    float* proj = (float*)w;    w += (size_t)S * 64 * 4;

    // degrees -> dis -> per-edge norm
    k_deg_init<<<(n_nodes + TPB - 1) / TPB, TPB, 0, stream>>>(dis, n_nodes);
    k_deg_accum<<<(n_edges + TPB - 1) / TPB, TPB, 0, stream>>>(dst, dis, n_edges);
    k_rsqrt_inplace<<<(n_nodes + TPB - 1) / TPB, TPB, 0, stream>>>(dis, n_nodes);
    k_norm<<<(n_edges + TPB - 1) / TPB, TPB, 0, stream>>>(src, dst, dis, nrm, n_edges);

#define LAYER(FI, FO, HIN, LIDX, RELU_FLAG)                                                   \
    do {                                                                                      \
        int total_mm = n_nodes * FO;                                                          \
        k_matmul<FI, FO><<<(total_mm + TPB - 1) / TPB, TPB, 0, stream>>>(HIN, Wl[LIDX], hB,   \
                                                                         n_nodes);            \
        k_selfloop<FO><<<(total_mm + TPB - 1) / TPB, TPB, 0, stream>>>(hB, dis, hA, n_nodes); \
        int total_e = n_edges * (FO / 4);                                                     \
        k_edge_agg<FO><<<(total_e + TPB - 1) / TPB, TPB, 0, stream>>>(src, dst, nrm, hB, hA,  \
                                                                      n_edges);               \
        hipMemsetAsync(stats, 0, 2 * FO * sizeof(float), stream);                             \
        k_bn_stats<FO><<<1024, TPB, 0, stream>>>(hA, stats, n_nodes);                         \
        if (RELU_FLAG)                                                                        \
            k_bn_apply<FO, true><<<(total_mm + TPB - 1) / TPB, TPB, 0, stream>>>(             \
                hA, stats, Gl[LIDX], BEl[LIDX], n_nodes);                                     \
        else                                                                                  \
            k_bn_apply<FO, false><<<(total_mm + TPB - 1) / TPB, TPB, 0, stream>>>(            \
                hA, stats, Gl[LIDX], BEl[LIDX], n_nodes);                                     \
    } while (0)

    LAYER(24, 8, x, 0, true);
    LAYER(8, 16, hA, 1, true);
    LAYER(16, 32, hA, 2, true);
    LAYER(32, 64, hA, 3, true);
    LAYER(64, 64, hA, 4, false);
#undef LAYER

    k_seg_off<<<(S + 1 + TPB - 1) / TPB, TPB, 0, stream>>>(bidx, n_nodes, seg_off, S);
    k_seg_reduce<<<S, TPB, 0, stream>>>(hA, seg_off, aggin);
    k_proj<<<S, 64, 0, stream>>>(aggin, Wp, bp, proj);
    int total_out = B * 64 * 196;
    k_pack<<<(total_out + TPB - 1) / TPB, TPB, 0, stream>>>(proj, num_sp, (float*)d_out, B, S);
}

// Round 2
// 2110.060 us; speedup vs baseline: 4.4180x; 4.4180x over previous
//
#include <hip/hip_runtime.h>

#define TPB 256
#define SCAN_ELEMS 4096  // elements per scan block (256 thr x 16)

// ---------------- degree histogram / dis ----------------

__global__ void k_hist(const int* __restrict__ dst, int* __restrict__ deg, int E) {
    int e = blockIdx.x * blockDim.x + threadIdx.x;
    if (e < E) atomicAdd(&deg[dst[e]], 1);
}

__global__ void k_dis(const int* __restrict__ deg, float* __restrict__ dis, int n) {
    int i = blockIdx.x * blockDim.x + threadIdx.x;
    if (i < n) dis[i] = rsqrtf((float)(deg[i] + 1));  // +1 self-loop
}

// ---------------- exclusive scan (row_ptr) ----------------

__global__ __launch_bounds__(256) void k_scan1(const int* __restrict__ deg, int n,
                                               int* __restrict__ out, int* __restrict__ blk_sum) {
    __shared__ int sh[256];
    int base = blockIdx.x * SCAN_ELEMS + threadIdx.x * 16;
    int v[16];
    int s = 0;
#pragma unroll
    for (int k = 0; k < 16; ++k) {
        int idx = base + k;
        int x = (idx < n) ? deg[idx] : 0;
        v[k] = s;  // local exclusive prefix
        s += x;
    }
    sh[threadIdx.x] = s;
    __syncthreads();
    for (int off = 1; off < 256; off <<= 1) {
        int t = (threadIdx.x >= off) ? sh[threadIdx.x - off] : 0;
        __syncthreads();
        sh[threadIdx.x] += t;
        __syncthreads();
    }
    int excl = (threadIdx.x == 0) ? 0 : sh[threadIdx.x - 1];
#pragma unroll
    for (int k = 0; k < 16; ++k) {
        int idx = base + k;
        if (idx < n) out[idx] = excl + v[k];
    }
    if (threadIdx.x == 255) blk_sum[blockIdx.x] = sh[255];
}

__global__ void k_scan2(const int* __restrict__ blk_sum, int* __restrict__ blk_off, int nblk) {
    if (threadIdx.x == 0 && blockIdx.x == 0) {
        int run = 0;
        for (int i = 0; i < nblk; ++i) {
            blk_off[i] = run;
            run += blk_sum[i];
        }
    }
}

__global__ void k_scan3(int* __restrict__ row_ptr, const int* __restrict__ blk_off, int n, int E,
                        int* __restrict__ cursor) {
    int i = blockIdx.x * blockDim.x + threadIdx.x;
    if (i < n) {
        int v = row_ptr[i] + blk_off[i / SCAN_ELEMS];
        row_ptr[i] = v;
        cursor[i] = v;
    } else if (i == n) {
        row_ptr[n] = E;
    }
}

// ---------------- CSR build ----------------

__global__ void k_scatter(const int* __restrict__ src, const int* __restrict__ dst,
                          int* __restrict__ cursor, int* __restrict__ csr_src, int E) {
    int e = blockIdx.x * blockDim.x + threadIdx.x;
    if (e >= E) return;
    int d = dst[e];
    int pos = atomicAdd(&cursor[d], 1);
    csr_src[pos] = src[e];
}

// ---------------- dense matmul h[N,FI] @ W[FI,FO] ----------------

template <int FI, int FO>
__global__ __launch_bounds__(TPB) void k_matmul(const float* __restrict__ h,
                                                const float* __restrict__ W,
                                                float* __restrict__ out, int n) {
    __shared__ float sW[FI * FO];
    for (int i = threadIdx.x; i < FI * FO; i += blockDim.x) sW[i] = W[i];
    __syncthreads();
    int idx = blockIdx.x * blockDim.x + threadIdx.x;
    int node = idx / FO;
    int j = idx % FO;
    if (node >= n) return;
    const float* row = h + (size_t)node * FI;
    float acc = 0.f;
#pragma unroll
    for (int k = 0; k < FI; ++k) acc = fmaf(row[k], sW[k * FO + j], acc);
    out[(size_t)node * FO + j] = acc;
}

// ---------------- GCN aggregation: CSR gather (no atomics) ----------------

// hA[d] = hB[d]*dis[d]^2 + sum_{s in adj(d)} hB[s]*dis[s]*dis[d], 4 channels/thread
template <int FO>
__global__ __launch_bounds__(TPB) void k_gather(const int* __restrict__ row_ptr,
                                                const int* __restrict__ csr_src,
                                                const float* __restrict__ dis,
                                                const float* __restrict__ hB,
                                                float* __restrict__ hA, int n) {
    constexpr int G = FO / 4;
    int idx = blockIdx.x * blockDim.x + threadIdx.x;
    int node = idx / G;
    int g = idx % G;
    if (node >= n) return;
    float dn = dis[node];
    const float4 h0 = *(const float4*)(hB + (size_t)node * FO + g * 4);
    float w0 = dn * dn;
    float4 acc;
    acc.x = h0.x * w0;
    acc.y = h0.y * w0;
    acc.z = h0.z * w0;
    acc.w = h0.w * w0;
    int beg = row_ptr[node], end = row_ptr[node + 1];
    for (int j = beg; j < end; ++j) {
        int s = csr_src[j];
        float w = dn * dis[s];
        const float4 v = *(const float4*)(hB + (size_t)s * FO + g * 4);
        acc.x = fmaf(v.x, w, acc.x);
        acc.y = fmaf(v.y, w, acc.y);
        acc.z = fmaf(v.z, w, acc.z);
        acc.w = fmaf(v.w, w, acc.w);
    }
    *(float4*)(hA + (size_t)node * FO + g * 4) = acc;
}

// ---------------- BatchNorm (training-mode batch stats) ----------------

template <int FO>
__global__ __launch_bounds__(TPB) void k_bn_stats(const float* __restrict__ h,
                                                  float* __restrict__ stats, int n) {
    int c = threadIdx.x % FO;
    const int rows_per = TPB / FO;
    int r0 = blockIdx.x * rows_per + threadIdx.x / FO;
    int rstride = gridDim.x * rows_per;
    float s = 0.f, s2 = 0.f;
    for (int r = r0; r < n; r += rstride) {
        float v = h[(size_t)r * FO + c];
        s += v;
        s2 += v * v;
    }
    __shared__ float ls[TPB], ls2[TPB];
    ls[threadIdx.x] = s;
    ls2[threadIdx.x] = s2;
    __syncthreads();
    if (threadIdx.x < FO) {
        float a = 0.f, b = 0.f;
        for (int t = threadIdx.x; t < TPB; t += FO) { a += ls[t]; b += ls2[t]; }
        atomicAdd(&stats[c], a);
        atomicAdd(&stats[FO + c], b);
    }
}

template <int FO, bool RELU>
__global__ void k_bn_apply(float* __restrict__ h, const float* __restrict__ stats,
                           const float* __restrict__ g, const float* __restrict__ be, int n) {
    int idx = blockIdx.x * blockDim.x + threadIdx.x;
    if (idx >= n * FO) return;
    int c = idx % FO;
    float inv_n = 1.0f / (float)n;
    float mu = stats[c] * inv_n;
    float var = stats[FO + c] * inv_n - mu * mu;
    float sc = g[c] * rsqrtf(var + 1e-5f);
    float v = (h[idx] - mu) * sc + be[c];
    h[idx] = RELU ? fmaxf(v, 0.f) : v;
}

// ---------------- segment multi-aggregation ----------------

__global__ void k_seg_off(const int* __restrict__ bidx, int n, int* __restrict__ seg_off, int S) {
    int s = blockIdx.x * blockDim.x + threadIdx.x;
    if (s > S) return;
    int lo = 0, hi = n;
    while (lo < hi) {
        int mid = (lo + hi) >> 1;
        if (bidx[mid] < s) lo = mid + 1; else hi = mid;
    }
    seg_off[s] = lo;
}

__global__ __launch_bounds__(TPB) void k_seg_reduce(const float* __restrict__ h,
                                                    const int* __restrict__ seg_off,
                                                    float* __restrict__ aggin) {
    int s = blockIdx.x;
    int start = seg_off[s], end = seg_off[s + 1];
    int c = threadIdx.x & 63;
    int r0 = start + (threadIdx.x >> 6);
    float sm = 0.f, sm2 = 0.f, mn = INFINITY, mx = -INFINITY;
    for (int r = r0; r < end; r += 4) {
        float v = h[(size_t)r * 64 + c];
        sm += v;
        sm2 += v * v;
        mn = fminf(mn, v);
        mx = fmaxf(mx, v);
    }
    __shared__ float s_sm[TPB], s_sm2[TPB], s_mn[TPB], s_mx[TPB];
    s_sm[threadIdx.x] = sm;
    s_sm2[threadIdx.x] = sm2;
    s_mn[threadIdx.x] = mn;
    s_mx[threadIdx.x] = mx;
    __syncthreads();
    if (threadIdx.x < 64) {
        for (int t = threadIdx.x + 64; t < TPB; t += 64) {
            sm += s_sm[t];
            sm2 += s_sm2[t];
            mn = fminf(mn, s_mn[t]);
            mx = fmaxf(mx, s_mx[t]);
        }
        int count = end - start;
        float cnt = (float)(count > 0 ? count : 1);
        float mean = sm / cnt;
        float var = sm2 / cnt - mean * mean;
        if (var < 0.f) var = 0.f;
        float sd = sqrtf(var + 1e-5f);
        if (count <= 0) { mn = 0.f; mx = 0.f; }
        aggin[s * 256 + c] = mean;
        aggin[s * 256 + 64 + c] = mn;
        aggin[s * 256 + 128 + c] = mx;
        aggin[s * 256 + 192 + c] = sd;
    }
}

__global__ __launch_bounds__(64) void k_proj(const float* __restrict__ aggin,
                                             const float* __restrict__ Wp,
                                             const float* __restrict__ bp,
                                             float* __restrict__ proj) {
    __shared__ float sA[256];
    int s = blockIdx.x;
    int j = threadIdx.x;
    for (int k = j; k < 256; k += 64) sA[k] = aggin[s * 256 + k];
    __syncthreads();
    float acc = bp[j];
#pragma unroll 8
    for (int k = 0; k < 256; ++k) acc = fmaf(sA[k], Wp[k * 64 + j], acc);
    proj[s * 64 + j] = acc;
}

__global__ void k_pack(const float* __restrict__ proj, const int* __restrict__ num_sp,
                       float* __restrict__ out, int B, int S) {
    int idx = blockIdx.x * blockDim.x + threadIdx.x;
    int total = B * 64 * 196;
    if (idx >= total) return;
    int ii = idx % 14;
    int jj = (idx / 14) % 14;
    int c = (idx / 196) % 64;
    int b = idx / (196 * 64);
    int p = ii * 14 + jj;
    int off = 0;
    for (int k = 0; k < b; ++k) off += num_sp[k];
    float v = 0.f;
    if (p < num_sp[b]) {
        int s = off + p;
        if (s > S - 1) s = S - 1;
        v = proj[s * 64 + c];
    }
    out[idx] = v;
}

// ---------------- launch ----------------

extern "C" void kernel_launch(void* const* d_in, const int* in_sizes, int n_in,
                              void* d_out, int out_size, void* d_ws, size_t ws_size,
                              hipStream_t stream) {
    const float* x = (const float*)d_in[0];
    const int* ei = (const int*)d_in[1];
    const int* bidx = (const int*)d_in[2];
    const int* num_sp = (const int*)d_in[3];
    const float* Wl[5], * Gl[5], * BEl[5];
    for (int i = 0; i < 5; ++i) {
        Wl[i] = (const float*)d_in[4 + 4 * i];
        // bias d_in[5+4*i] skipped: per-channel constant cancels in training-mode BN
        Gl[i] = (const float*)d_in[6 + 4 * i];
        BEl[i] = (const float*)d_in[7 + 4 * i];
    }
    const float* Wp = (const float*)d_in[24];
    const float* bp = (const float*)d_in[25];

    const int n_nodes = in_sizes[0] / 24;
    const int n_edges = in_sizes[1] / 2;
    const int B = in_sizes[3];
    const int S = 1200;  // B * NUM_SP
    const int* src = ei;
    const int* dst = ei + n_edges;

    const int n_scan_blk = (n_nodes + SCAN_ELEMS - 1) / SCAN_ELEMS;

    // workspace carve (all chunks >=256B-aligned)
    char* w = (char*)d_ws;
    float* hA = (float*)w;      w += (size_t)n_nodes * 64 * 4;
    float* hB = (float*)w;      w += (size_t)n_nodes * 64 * 4;
    float* dis = (float*)w;     w += (size_t)n_nodes * 4;
    int* deg = (int*)w;         w += (size_t)n_nodes * 4;
    int* row_ptr = (int*)w;     w += (size_t)(n_nodes + 64) * 4;
    int* cursor = (int*)w;      w += (size_t)n_nodes * 4;
    int* csr_src = (int*)w;     w += (size_t)n_edges * 4;
    int* blk_sum = (int*)w;     w += (size_t)n_scan_blk * 4 + 256;
    int* blk_off = (int*)w;     w += (size_t)n_scan_blk * 4 + 256;
    float* stats = (float*)w;   w += 1024;
    int* seg_off = (int*)w;     w += 8192;
    float* aggin = (float*)w;   w += (size_t)S * 256 * 4;
    float* proj = (float*)w;    w += (size_t)S * 64 * 4;

    // ---- CSR build: deg -> dis, row_ptr (scan), scatter ----
    hipMemsetAsync(deg, 0, (size_t)n_nodes * 4, stream);
    k_hist<<<(n_edges + TPB - 1) / TPB, TPB, 0, stream>>>(dst, deg, n_edges);
    k_dis<<<(n_nodes + TPB - 1) / TPB, TPB, 0, stream>>>(deg, dis, n_nodes);
    k_scan1<<<n_scan_blk, 256, 0, stream>>>(deg, n_nodes, row_ptr, blk_sum);
    k_scan2<<<1, 64, 0, stream>>>(blk_sum, blk_off, n_scan_blk);
    k_scan3<<<(n_nodes + 1 + TPB - 1) / TPB, TPB, 0, stream>>>(row_ptr, blk_off, n_nodes,
                                                               n_edges, cursor);
    k_scatter<<<(n_edges + TPB - 1) / TPB, TPB, 0, stream>>>(src, dst, cursor, csr_src, n_edges);

#define LAYER(FI, FO, HIN, LIDX, RELU_FLAG)                                                   \
    do {                                                                                      \
        int total_mm = n_nodes * FO;                                                          \
        k_matmul<FI, FO><<<(total_mm + TPB - 1) / TPB, TPB, 0, stream>>>(HIN, Wl[LIDX], hB,   \
                                                                         n_nodes);            \
        int total_g = n_nodes * (FO / 4);                                                     \
        k_gather<FO><<<(total_g + TPB - 1) / TPB, TPB, 0, stream>>>(row_ptr, csr_src, dis,    \
                                                                    hB, hA, n_nodes);         \
        hipMemsetAsync(stats, 0, 2 * FO * sizeof(float), stream);                             \
        k_bn_stats<FO><<<1024, TPB, 0, stream>>>(hA, stats, n_nodes);                         \
        if (RELU_FLAG)                                                                        \
            k_bn_apply<FO, true><<<(total_mm + TPB - 1) / TPB, TPB, 0, stream>>>(             \
                hA, stats, Gl[LIDX], BEl[LIDX], n_nodes);                                     \
        else                                                                                  \
            k_bn_apply<FO, false><<<(total_mm + TPB - 1) / TPB, TPB, 0, stream>>>(            \
                hA, stats, Gl[LIDX], BEl[LIDX], n_nodes);                                     \
    } while (0)

    LAYER(24, 8, x, 0, true);
    LAYER(8, 16, hA, 1, true);
    LAYER(16, 32, hA, 2, true);
    LAYER(32, 64, hA, 3, true);
    LAYER(64, 64, hA, 4, false);
#undef LAYER

    k_seg_off<<<(S + 1 + TPB - 1) / TPB, TPB, 0, stream>>>(bidx, n_nodes, seg_off, S);
    k_seg_reduce<<<S, TPB, 0, stream>>>(hA, seg_off, aggin);
    k_proj<<<S, 64, 0, stream>>>(aggin, Wp, bp, proj);
    int total_out = B * 64 * 196;
    k_pack<<<(total_out + TPB - 1) / TPB, TPB, 0, stream>>>(proj, num_sp, (float*)d_out, B, S);
}

// Round 3
// 1608.068 us; speedup vs baseline: 5.7972x; 1.3122x over previous
//
#include <hip/hip_runtime.h>

#define TPB 256
#define SCAN_ELEMS 4096

// ---------------- small float4 helpers ----------------

__device__ inline float4 f4z() { return make_float4(0.f, 0.f, 0.f, 0.f); }
__device__ inline float4 f4axpy(float4 a, float s, float4 c) {
    return make_float4(fmaf(a.x, s, c.x), fmaf(a.y, s, c.y), fmaf(a.z, s, c.z), fmaf(a.w, s, c.w));
}
__device__ inline float4 f4relu_aff(float4 h, float4 sc, float4 sb) {
    return make_float4(fmaxf(fmaf(h.x, sc.x, sb.x), 0.f), fmaxf(fmaf(h.y, sc.y, sb.y), 0.f),
                       fmaxf(fmaf(h.z, sc.z, sb.z), 0.f), fmaxf(fmaf(h.w, sc.w, sb.w), 0.f));
}

// ---------------- degree / dis ----------------

__global__ void k_hist(const int* __restrict__ dst, int* __restrict__ deg, int E) {
    int e = blockIdx.x * blockDim.x + threadIdx.x;
    if (e < E) atomicAdd(&deg[dst[e]], 1);
}

__global__ void k_dis(const int* __restrict__ deg, float* __restrict__ dis, int n) {
    int i = blockIdx.x * blockDim.x + threadIdx.x;
    if (i < n) dis[i] = rsqrtf((float)(deg[i] + 1));  // +1 self-loop
}

// ---------------- exclusive scan (row_ptr) ----------------

__global__ __launch_bounds__(256) void k_scan1(const int* __restrict__ deg, int n,
                                               int* __restrict__ out, int* __restrict__ blk_sum) {
    __shared__ int sh[256];
    int base = blockIdx.x * SCAN_ELEMS + threadIdx.x * 16;
    int v[16];
    int s = 0;
#pragma unroll
    for (int k = 0; k < 16; ++k) {
        int idx = base + k;
        int x = (idx < n) ? deg[idx] : 0;
        v[k] = s;
        s += x;
    }
    sh[threadIdx.x] = s;
    __syncthreads();
    for (int off = 1; off < 256; off <<= 1) {
        int t = (threadIdx.x >= off) ? sh[threadIdx.x - off] : 0;
        __syncthreads();
        sh[threadIdx.x] += t;
        __syncthreads();
    }
    int excl = (threadIdx.x == 0) ? 0 : sh[threadIdx.x - 1];
#pragma unroll
    for (int k = 0; k < 16; ++k) {
        int idx = base + k;
        if (idx < n) out[idx] = excl + v[k];
    }
    if (threadIdx.x == 255) blk_sum[blockIdx.x] = sh[255];
}

__global__ void k_scan2(const int* __restrict__ blk_sum, int* __restrict__ blk_off, int nblk) {
    if (threadIdx.x == 0 && blockIdx.x == 0) {
        int run = 0;
        for (int i = 0; i < nblk; ++i) {
            blk_off[i] = run;
            run += blk_sum[i];
        }
    }
}

__global__ void k_scan3(int* __restrict__ row_ptr, const int* __restrict__ blk_off, int n, int E,
                        int* __restrict__ cursor) {
    int i = blockIdx.x * blockDim.x + threadIdx.x;
    if (i < n) {
        int v = row_ptr[i] + blk_off[i / SCAN_ELEMS];
        row_ptr[i] = v;
        cursor[i] = v;
    } else if (i == n) {
        row_ptr[n] = E;
    }
}

__global__ void k_scatter(const int* __restrict__ src, const int* __restrict__ dst,
                          int* __restrict__ cursor, int* __restrict__ csr_src, int E) {
    int e = blockIdx.x * blockDim.x + threadIdx.x;
    if (e >= E) return;
    int d = dst[e];
    int pos = atomicAdd(&cursor[d], 1);
    csr_src[pos] = src[e];
}

// ---------------- register-tiled matmul z = t @ W, optional fused BN stats ----------------
// thread: 4 nodes x 8 channels. stats layout: [sum(FO) | sumsq(FO)]

template <int FI, int FO, bool STATS>
__global__ __launch_bounds__(TPB) void k_mm(const float* __restrict__ t,
                                            const float* __restrict__ W,
                                            float* __restrict__ z, float* __restrict__ stats,
                                            int n) {
    constexpr int GROUPS = FO / 8;
    constexpr int NPB = (TPB / GROUPS) * 4;
    __shared__ float sW[FI * FO];
    __shared__ float sred[TPB * 16];
    for (int i = threadIdx.x; i < FI * FO; i += TPB) sW[i] = W[i];
    __syncthreads();

    const int g = threadIdx.x % GROUPS;
    const int nl = threadIdx.x / GROUPS;
    const int nbase = blockIdx.x * NPB + nl * 4;

    float4 acc0[4], acc1[4];
#pragma unroll
    for (int j = 0; j < 4; ++j) { acc0[j] = f4z(); acc1[j] = f4z(); }

    for (int k = 0; k < FI; k += 4) {
        float4 wv0[4], wv1[4];
#pragma unroll
        for (int kk = 0; kk < 4; ++kk) {
            wv0[kk] = *(const float4*)&sW[(k + kk) * FO + g * 8];
            wv1[kk] = *(const float4*)&sW[(k + kk) * FO + g * 8 + 4];
        }
#pragma unroll
        for (int j = 0; j < 4; ++j) {
            int node = nbase + j;
            float4 rv = f4z();
            if (node < n) rv = *(const float4*)(t + (size_t)node * FI + k);
            float rk[4] = {rv.x, rv.y, rv.z, rv.w};
#pragma unroll
            for (int kk = 0; kk < 4; ++kk) {
                acc0[j] = f4axpy(wv0[kk], rk[kk], acc0[j]);
                acc1[j] = f4axpy(wv1[kk], rk[kk], acc1[j]);
            }
        }
    }

#pragma unroll
    for (int j = 0; j < 4; ++j) {
        int node = nbase + j;
        if (node < n) {
            *(float4*)(z + (size_t)node * FO + g * 8) = acc0[j];
            *(float4*)(z + (size_t)node * FO + g * 8 + 4) = acc1[j];
        }
    }

    if (STATS) {
        float4 s0 = f4z(), s1 = f4z(), q0 = f4z(), q1 = f4z();
#pragma unroll
        for (int j = 0; j < 4; ++j) {
            s0.x += acc0[j].x; s0.y += acc0[j].y; s0.z += acc0[j].z; s0.w += acc0[j].w;
            s1.x += acc1[j].x; s1.y += acc1[j].y; s1.z += acc1[j].z; s1.w += acc1[j].w;
            q0 = f4axpy(acc0[j], 1.f, q0), q0 = f4z(), q0 = q0;  // placeholder avoid
        }
        // recompute squares properly
        q0 = f4z(); q1 = f4z();
#pragma unroll
        for (int j = 0; j < 4; ++j) {
            q0.x = fmaf(acc0[j].x, acc0[j].x, q0.x); q0.y = fmaf(acc0[j].y, acc0[j].y, q0.y);
            q0.z = fmaf(acc0[j].z, acc0[j].z, q0.z); q0.w = fmaf(acc0[j].w, acc0[j].w, q0.w);
            q1.x = fmaf(acc1[j].x, acc1[j].x, q1.x); q1.y = fmaf(acc1[j].y, acc1[j].y, q1.y);
            q1.z = fmaf(acc1[j].z, acc1[j].z, q1.z); q1.w = fmaf(acc1[j].w, acc1[j].w, q1.w);
        }
        float* slot = &sred[threadIdx.x * 16];
        *(float4*)(slot + 0) = s0;
        *(float4*)(slot + 4) = s1;
        *(float4*)(slot + 8) = q0;
        *(float4*)(slot + 12) = q1;
        __syncthreads();
        if (threadIdx.x < FO * 2) {
            int c = threadIdx.x % FO;
            int m = threadIdx.x / FO;
            int g2 = c / 8, ci = c % 8;
            float a = 0.f;
            for (int nl2 = 0; nl2 < TPB / GROUPS; ++nl2)
                a += sred[(nl2 * GROUPS + g2) * 16 + m * 8 + ci];
            atomicAdd(&stats[m * FO + c], a);
        }
    }
}

// ---------------- CSR gather, optional fused BN-affine+ReLU on input ----------------
// thread: one node x GW channels (GW = min(F,32)); t[d] = w0*h[d] + sum w_e*h[s]
// where h = AFFINE ? relu(z*sc+sb) : z

template <int F, bool AFFINE>
__global__ __launch_bounds__(TPB) void k_gather(const int* __restrict__ row_ptr,
                                                const int* __restrict__ csr_src,
                                                const float* __restrict__ dis,
                                                const float* __restrict__ z,
                                                float* __restrict__ t,
                                                const float* __restrict__ stats,
                                                const float* __restrict__ gg,
                                                const float* __restrict__ be, float inv_n,
                                                int n) {
    constexpr int GW = (F < 32) ? F : 32;
    constexpr int PARTS = F / GW;
    constexpr int NV = GW / 4;
    int tid = blockIdx.x * blockDim.x + threadIdx.x;
    int node = tid / PARTS;
    int part = tid % PARTS;
    if (node >= n) return;
    const int cbase = part * GW;

    float4 sc[NV], sb[NV];
    if (AFFINE) {
#pragma unroll
        for (int v = 0; v < NV; ++v) {
            float scv[4], sbv[4];
#pragma unroll
            for (int u = 0; u < 4; ++u) {
                int c = cbase + v * 4 + u;
                float mu = stats[c] * inv_n;
                float var = stats[F + c] * inv_n - mu * mu;
                float s = gg[c] * rsqrtf(var + 1e-5f);
                scv[u] = s;
                sbv[u] = fmaf(-mu, s, be[c]);
            }
            sc[v] = make_float4(scv[0], scv[1], scv[2], scv[3]);
            sb[v] = make_float4(sbv[0], sbv[1], sbv[2], sbv[3]);
        }
    }

    float dn = dis[node];
    float w0 = dn * dn;
    float4 acc[NV];
    {
        const float4* zp = (const float4*)(z + (size_t)node * F + cbase);
#pragma unroll
        for (int v = 0; v < NV; ++v) {
            float4 hv = zp[v];
            if (AFFINE) hv = f4relu_aff(hv, sc[v], sb[v]);
            acc[v] = make_float4(hv.x * w0, hv.y * w0, hv.z * w0, hv.w * w0);
        }
    }
    int beg = row_ptr[node], end = row_ptr[node + 1];
    for (int j = beg; j < end; ++j) {
        int s = csr_src[j];
        float w = dn * dis[s];
        const float4* zp = (const float4*)(z + (size_t)s * F + cbase);
#pragma unroll
        for (int v = 0; v < NV; ++v) {
            float4 hv = zp[v];
            if (AFFINE) hv = f4relu_aff(hv, sc[v], sb[v]);
            acc[v] = f4axpy(hv, w, acc[v]);
        }
    }
    float4* tp = (float4*)(t + (size_t)node * F + cbase);
#pragma unroll
    for (int v = 0; v < NV; ++v) tp[v] = acc[v];
}

// ---------------- standalone BN stats (layer 1 only: z produced by gather) ----------------

template <int FO>
__global__ __launch_bounds__(TPB) void k_bn_stats(const float* __restrict__ h,
                                                  float* __restrict__ stats, int n) {
    int c = threadIdx.x % FO;
    const int rows_per = TPB / FO;
    int r0 = blockIdx.x * rows_per + threadIdx.x / FO;
    int rstride = gridDim.x * rows_per;
    float s = 0.f, s2 = 0.f;
    for (int r = r0; r < n; r += rstride) {
        float v = h[(size_t)r * FO + c];
        s += v;
        s2 += v * v;
    }
    __shared__ float ls[TPB], ls2[TPB];
    ls[threadIdx.x] = s;
    ls2[threadIdx.x] = s2;
    __syncthreads();
    if (threadIdx.x < FO) {
        float a = 0.f, b = 0.f;
        for (int t = threadIdx.x; t < TPB; t += FO) { a += ls[t]; b += ls2[t]; }
        atomicAdd(&stats[c], a);
        atomicAdd(&stats[FO + c], b);
    }
}

// ---------------- segment multi-aggregation (applies final BN affine, no relu) ----------------

__global__ void k_seg_off(const int* __restrict__ bidx, int n, int* __restrict__ seg_off, int S) {
    int s = blockIdx.x * blockDim.x + threadIdx.x;
    if (s > S) return;
    int lo = 0, hi = n;
    while (lo < hi) {
        int mid = (lo + hi) >> 1;
        if (bidx[mid] < s) lo = mid + 1; else hi = mid;
    }
    seg_off[s] = lo;
}

__global__ __launch_bounds__(TPB) void k_seg_reduce(const float* __restrict__ z,
                                                    const int* __restrict__ seg_off,
                                                    float* __restrict__ aggin,
                                                    const float* __restrict__ stats,
                                                    const float* __restrict__ gg,
                                                    const float* __restrict__ be, float inv_n) {
    int s = blockIdx.x;
    int start = seg_off[s], end = seg_off[s + 1];
    int c = threadIdx.x & 63;
    float mu = stats[c] * inv_n;
    float var = stats[64 + c] * inv_n - mu * mu;
    float scv = gg[c] * rsqrtf(var + 1e-5f);
    float sbv = fmaf(-mu, scv, be[c]);
    int r0 = start + (threadIdx.x >> 6);
    float sm = 0.f, sm2 = 0.f, mn = INFINITY, mx = -INFINITY;
    for (int r = r0; r < end; r += 4) {
        float v = fmaf(z[(size_t)r * 64 + c], scv, sbv);
        sm += v;
        sm2 = fmaf(v, v, sm2);
        mn = fminf(mn, v);
        mx = fmaxf(mx, v);
    }
    __shared__ float s_sm[TPB], s_sm2[TPB], s_mn[TPB], s_mx[TPB];
    s_sm[threadIdx.x] = sm;
    s_sm2[threadIdx.x] = sm2;
    s_mn[threadIdx.x] = mn;
    s_mx[threadIdx.x] = mx;
    __syncthreads();
    if (threadIdx.x < 64) {
        for (int t = threadIdx.x + 64; t < TPB; t += 64) {
            sm += s_sm[t];
            sm2 += s_sm2[t];
            mn = fminf(mn, s_mn[t]);
            mx = fmaxf(mx, s_mx[t]);
        }
        int count = end - start;
        float cnt = (float)(count > 0 ? count : 1);
        float mean = sm / cnt;
        float var2 = sm2 / cnt - mean * mean;
        if (var2 < 0.f) var2 = 0.f;
        float sd = sqrtf(var2 + 1e-5f);
        if (count <= 0) { mn = 0.f; mx = 0.f; }
        aggin[s * 256 + c] = mean;
        aggin[s * 256 + 64 + c] = mn;
        aggin[s * 256 + 128 + c] = mx;
        aggin[s * 256 + 192 + c] = sd;
    }
}

__global__ __launch_bounds__(64) void k_proj(const float* __restrict__ aggin,
                                             const float* __restrict__ Wp,
                                             const float* __restrict__ bp,
                                             float* __restrict__ proj) {
    __shared__ float sA[256];
    int s = blockIdx.x;
    int j = threadIdx.x;
    for (int k = j; k < 256; k += 64) sA[k] = aggin[s * 256 + k];
    __syncthreads();
    float acc = bp[j];
#pragma unroll 8
    for (int k = 0; k < 256; ++k) acc = fmaf(sA[k], Wp[k * 64 + j], acc);
    proj[s * 64 + j] = acc;
}

__global__ void k_pack(const float* __restrict__ proj, const int* __restrict__ num_sp,
                       float* __restrict__ out, int B, int S) {
    int idx = blockIdx.x * blockDim.x + threadIdx.x;
    int total = B * 64 * 196;
    if (idx >= total) return;
    int ii = idx % 14;
    int jj = (idx / 14) % 14;
    int c = (idx / 196) % 64;
    int b = idx / (196 * 64);
    int p = ii * 14 + jj;
    int off = 0;
    for (int k = 0; k < b; ++k) off += num_sp[k];
    float v = 0.f;
    if (p < num_sp[b]) {
        int s = off + p;
        if (s > S - 1) s = S - 1;
        v = proj[s * 64 + c];
    }
    out[idx] = v;
}

// ---------------- launch ----------------

extern "C" void kernel_launch(void* const* d_in, const int* in_sizes, int n_in,
                              void* d_out, int out_size, void* d_ws, size_t ws_size,
                              hipStream_t stream) {
    const float* x = (const float*)d_in[0];
    const int* ei = (const int*)d_in[1];
    const int* bidx = (const int*)d_in[2];
    const int* num_sp = (const int*)d_in[3];
    const float* Wl[5], * Gl[5], * BEl[5];
    for (int i = 0; i < 5; ++i) {
        Wl[i] = (const float*)d_in[4 + 4 * i];
        // bias skipped: per-channel constant cancels in training-mode BN
        Gl[i] = (const float*)d_in[6 + 4 * i];
        BEl[i] = (const float*)d_in[7 + 4 * i];
    }
    const float* Wp = (const float*)d_in[24];
    const float* bp = (const float*)d_in[25];

    const int n = in_sizes[0] / 24;
    const int E = in_sizes[1] / 2;
    const int B = in_sizes[3];
    const int S = 1200;
    const int* src = ei;
    const int* dst = ei + E;
    const float inv_n = 1.0f / (float)n;
    const int n_scan_blk = (n + SCAN_ELEMS - 1) / SCAN_ELEMS;

    char* w = (char*)d_ws;
    float* bufZ = (float*)w;    w += (size_t)n * 64 * 4;
    float* bufT = (float*)w;    w += (size_t)n * 64 * 4;
    float* dis = (float*)w;     w += (size_t)n * 4;
    int* deg = (int*)w;         w += (size_t)n * 4;
    int* row_ptr = (int*)w;     w += (size_t)(n + 64) * 4;
    int* cursor = (int*)w;      w += (size_t)n * 4;
    int* csr_src = (int*)w;     w += (size_t)E * 4;
    int* blk_sum = (int*)w;     w += (size_t)n_scan_blk * 4 + 256;
    int* blk_off = (int*)w;     w += (size_t)n_scan_blk * 4 + 256;
    float* stats_all = (float*)w; w += 5 * 128 * 4;
    int* seg_off = (int*)w;     w += 8192;
    float* aggin = (float*)w;   w += (size_t)S * 256 * 4;
    float* proj = (float*)w;    w += (size_t)S * 64 * 4;
    float* st0 = stats_all;        // 2*8
    float* st1 = stats_all + 128;  // 2*16
    float* st2 = stats_all + 256;  // 2*32
    float* st3 = stats_all + 384;  // 2*64
    float* st4 = stats_all + 512;  // 2*64

    // CSR build
    hipMemsetAsync(deg, 0, (size_t)n * 4, stream);
    hipMemsetAsync(stats_all, 0, 5 * 128 * 4, stream);
    k_hist<<<(E + TPB - 1) / TPB, TPB, 0, stream>>>(dst, deg, E);
    k_dis<<<(n + TPB - 1) / TPB, TPB, 0, stream>>>(deg, dis, n);
    k_scan1<<<n_scan_blk, 256, 0, stream>>>(deg, n, row_ptr, blk_sum);
    k_scan2<<<1, 64, 0, stream>>>(blk_sum, blk_off, n_scan_blk);
    k_scan3<<<(n + 1 + TPB - 1) / TPB, TPB, 0, stream>>>(row_ptr, blk_off, n, E, cursor);
    k_scatter<<<(E + TPB - 1) / TPB, TPB, 0, stream>>>(src, dst, cursor, csr_src, E);

    // Layer 1: m = x@W1 (no stats) ; z1 = Agg(m) ; stats(z1)
    k_mm<24, 8, false><<<(n + 1023) / 1024, TPB, 0, stream>>>(x, Wl[0], bufT, nullptr, n);
    k_gather<8, false><<<(n + TPB - 1) / TPB, TPB, 0, stream>>>(
        row_ptr, csr_src, dis, bufT, bufZ, nullptr, nullptr, nullptr, inv_n, n);
    k_bn_stats<8><<<1024, TPB, 0, stream>>>(bufZ, st0, n);

    // Layers 2-5: t = Agg(relu(bn_{i-1}(z))) ; z = t@W_i (stats fused)
    k_gather<8, true><<<(n + TPB - 1) / TPB, TPB, 0, stream>>>(
        row_ptr, csr_src, dis, bufZ, bufT, st0, Gl[0], BEl[0], inv_n, n);
    k_mm<8, 16, true><<<(n + 511) / 512, TPB, 0, stream>>>(bufT, Wl[1], bufZ, st1, n);

    k_gather<16, true><<<(n + TPB - 1) / TPB, TPB, 0, stream>>>(
        row_ptr, csr_src, dis, bufZ, bufT, st1, Gl[1], BEl[1], inv_n, n);
    k_mm<16, 32, true><<<(n + 255) / 256, TPB, 0, stream>>>(bufT, Wl[2], bufZ, st2, n);

    k_gather<32, true><<<(n + TPB - 1) / TPB, TPB, 0, stream>>>(
        row_ptr, csr_src, dis, bufZ, bufT, st2, Gl[2], BEl[2], inv_n, n);
    k_mm<32, 64, true><<<(n + 127) / 128, TPB, 0, stream>>>(bufT, Wl[3], bufZ, st3, n);

    k_gather<64, true><<<(2 * n + TPB - 1) / TPB, TPB, 0, stream>>>(
        row_ptr, csr_src, dis, bufZ, bufT, st3, Gl[3], BEl[3], inv_n, n);
    k_mm<64, 64, true><<<(n + 127) / 128, TPB, 0, stream>>>(bufT, Wl[4], bufZ, st4, n);

    // tail: segment multi-agg (applies BN5 affine, no relu) -> proj -> pack
    k_seg_off<<<(S + 1 + TPB - 1) / TPB, TPB, 0, stream>>>(bidx, n, seg_off, S);
    k_seg_reduce<<<S, TPB, 0, stream>>>(bufZ, seg_off, aggin, st4, Gl[4], BEl[4], inv_n);
    k_proj<<<S, 64, 0, stream>>>(aggin, Wp, bp, proj);
    int total_out = B * 64 * 196;
    k_pack<<<(total_out + TPB - 1) / TPB, TPB, 0, stream>>>(proj, num_sp, (float*)d_out, B, S);
}

// Round 4
// 1334.852 us; speedup vs baseline: 6.9838x; 1.2047x over previous
//
#include <hip/hip_runtime.h>
#include <hip/hip_fp16.h>

#define TPB 256
#define SCAN_ELEMS 4096
#define BSH 10  // 1024 nodes per bucket

// ---------------- half helpers ----------------

union H8 { uint4 u; __half2 h[4]; };
union H4 { uint2 u; __half2 h[2]; };

__device__ inline void h8_to_f(const H8 v, float4& a, float4& b) {
    float2 f0 = __half22float2(v.h[0]);
    float2 f1 = __half22float2(v.h[1]);
    float2 f2 = __half22float2(v.h[2]);
    float2 f3 = __half22float2(v.h[3]);
    a = make_float4(f0.x, f0.y, f1.x, f1.y);
    b = make_float4(f2.x, f2.y, f3.x, f3.y);
}
__device__ inline H8 f_to_h8(float4 a, float4 b) {
    H8 r;
    r.h[0] = __floats2half2_rn(a.x, a.y);
    r.h[1] = __floats2half2_rn(a.z, a.w);
    r.h[2] = __floats2half2_rn(b.x, b.y);
    r.h[3] = __floats2half2_rn(b.z, b.w);
    return r;
}
__device__ inline float4 f4z() { return make_float4(0.f, 0.f, 0.f, 0.f); }
__device__ inline float4 f4axpy(float4 a, float s, float4 c) {
    return make_float4(fmaf(a.x, s, c.x), fmaf(a.y, s, c.y), fmaf(a.z, s, c.z), fmaf(a.w, s, c.w));
}
__device__ inline float4 f4relu_aff(float4 h, float4 sc, float4 sb) {
    return make_float4(fmaxf(fmaf(h.x, sc.x, sb.x), 0.f), fmaxf(fmaf(h.y, sc.y, sb.y), 0.f),
                       fmaxf(fmaf(h.z, sc.z, sb.z), 0.f), fmaxf(fmaf(h.w, sc.w, sb.w), 0.f));
}

// ---------------- degree / dis ----------------

__global__ void k_hist(const int* __restrict__ dst, int* __restrict__ deg, int E) {
    int e = blockIdx.x * blockDim.x + threadIdx.x;
    if (e < E) atomicAdd(&deg[dst[e]], 1);
}

__global__ void k_dis(const int* __restrict__ deg, float* __restrict__ dis, int n) {
    int i = blockIdx.x * blockDim.x + threadIdx.x;
    if (i < n) dis[i] = rsqrtf((float)(deg[i] + 1));  // +1 self-loop
}

// ---------------- exclusive scan (row_ptr) ----------------

__global__ __launch_bounds__(256) void k_scan1(const int* __restrict__ deg, int n,
                                               int* __restrict__ out, int* __restrict__ blk_sum) {
    __shared__ int sh[256];
    int base = blockIdx.x * SCAN_ELEMS + threadIdx.x * 16;
    int v[16];
    int s = 0;
#pragma unroll
    for (int k = 0; k < 16; ++k) {
        int idx = base + k;
        int x = (idx < n) ? deg[idx] : 0;
        v[k] = s;
        s += x;
    }
    sh[threadIdx.x] = s;
    __syncthreads();
    for (int off = 1; off < 256; off <<= 1) {
        int t = (threadIdx.x >= off) ? sh[threadIdx.x - off] : 0;
        __syncthreads();
        sh[threadIdx.x] += t;
        __syncthreads();
    }
    int excl = (threadIdx.x == 0) ? 0 : sh[threadIdx.x - 1];
#pragma unroll
    for (int k = 0; k < 16; ++k) {
        int idx = base + k;
        if (idx < n) out[idx] = excl + v[k];
    }
    if (threadIdx.x == 255) blk_sum[blockIdx.x] = sh[255];
}

__global__ void k_scan2(const int* __restrict__ blk_sum, int* __restrict__ blk_off, int nblk) {
    if (threadIdx.x == 0 && blockIdx.x == 0) {
        int run = 0;
        for (int i = 0; i < nblk; ++i) {
            blk_off[i] = run;
            run += blk_sum[i];
        }
    }
}

__global__ void k_scan3(int* __restrict__ row_ptr, const int* __restrict__ blk_off, int n, int E,
                        int* __restrict__ cursor) {
    int i = blockIdx.x * blockDim.x + threadIdx.x;
    if (i < n) {
        int v = row_ptr[i] + blk_off[i / SCAN_ELEMS];
        row_ptr[i] = v;
        cursor[i] = v;
    } else if (i == n) {
        row_ptr[n] = E;
    }
}

// ---------------- radix-partitioned CSR build ----------------

__global__ void k_bucket_init(const int* __restrict__ row_ptr, int* __restrict__ bcur, int n,
                              int nb) {
    int b = blockIdx.x * blockDim.x + threadIdx.x;
    if (b < nb) {
        int node = b << BSH;
        if (node > n) node = n;
        bcur[b] = row_ptr[node];
    }
}

// pass A: bin edges by dst bucket; bins land directly in final CSR windows (unordered)
__global__ __launch_bounds__(256) void k_partA(const int* __restrict__ src,
                                               const int* __restrict__ dst, int E,
                                               int* __restrict__ bcur, int2* __restrict__ bin,
                                               int nb) {
    __shared__ int hist[1024];
    __shared__ int base[1024];
    for (int i = threadIdx.x; i < nb; i += 256) hist[i] = 0;
    __syncthreads();
    const int e0 = blockIdx.x * 8192;
#pragma unroll 4
    for (int k = 0; k < 32; ++k) {
        int e = e0 + k * 256 + threadIdx.x;
        if (e < E) atomicAdd(&hist[dst[e] >> BSH], 1);
    }
    __syncthreads();
    for (int i = threadIdx.x; i < nb; i += 256) {
        int h = hist[i];
        base[i] = h ? atomicAdd(&bcur[i], h) : 0;
        hist[i] = 0;
    }
    __syncthreads();
#pragma unroll 4
    for (int k = 0; k < 32; ++k) {
        int e = e0 + k * 256 + threadIdx.x;
        if (e < E) {
            int d = dst[e];
            int b = d >> BSH;
            int off = atomicAdd(&hist[b], 1);
            bin[base[b] + off] = make_int2(src[e], d);
        }
    }
}

// pass B: within-bucket scatter; cursor + csr writes confined to ~32KB windows
__global__ void k_partB(const int2* __restrict__ bin, int* __restrict__ cursor,
                        int* __restrict__ csr_src, int E) {
    int i = blockIdx.x * blockDim.x + threadIdx.x;
    if (i >= E) return;
    int2 p = bin[i];
    int pos = atomicAdd(&cursor[p.y], 1);
    csr_src[pos] = p.x;
}

// ---------------- register-tiled matmul z = t @ W (half out), optional fused BN stats -----

template <int FI, int FO, bool STATS, bool IN_F32>
__global__ __launch_bounds__(TPB) void k_mm(const void* __restrict__ tin,
                                            const float* __restrict__ W, __half* __restrict__ z,
                                            float* __restrict__ stats, int n) {
    constexpr int GROUPS = FO / 8;
    constexpr int NPB = (TPB / GROUPS) * 4;
    __shared__ float sW[FI * FO];
    __shared__ float sred[STATS ? TPB * 16 : 1];
    for (int i = threadIdx.x; i < FI * FO; i += TPB) sW[i] = W[i];
    __syncthreads();

    const int g = threadIdx.x % GROUPS;
    const int nl = threadIdx.x / GROUPS;
    const int nbase = blockIdx.x * NPB + nl * 4;

    float4 acc0[4], acc1[4];
#pragma unroll
    for (int j = 0; j < 4; ++j) { acc0[j] = f4z(); acc1[j] = f4z(); }

    for (int k = 0; k < FI; k += 4) {
        float4 wv0[4], wv1[4];
#pragma unroll
        for (int kk = 0; kk < 4; ++kk) {
            wv0[kk] = *(const float4*)&sW[(k + kk) * FO + g * 8];
            wv1[kk] = *(const float4*)&sW[(k + kk) * FO + g * 8 + 4];
        }
#pragma unroll
        for (int j = 0; j < 4; ++j) {
            int node = nbase + j;
            float rk[4] = {0.f, 0.f, 0.f, 0.f};
            if (node < n) {
                if (IN_F32) {
                    float4 rv = *(const float4*)((const float*)tin + (size_t)node * FI + k);
                    rk[0] = rv.x; rk[1] = rv.y; rk[2] = rv.z; rk[3] = rv.w;
                } else {
                    H4 hv;
                    hv.u = *(const uint2*)((const __half*)tin + (size_t)node * FI + k);
                    float2 f0 = __half22float2(hv.h[0]);
                    float2 f1 = __half22float2(hv.h[1]);
                    rk[0] = f0.x; rk[1] = f0.y; rk[2] = f1.x; rk[3] = f1.y;
                }
            }
#pragma unroll
            for (int kk = 0; kk < 4; ++kk) {
                acc0[j] = f4axpy(wv0[kk], rk[kk], acc0[j]);
                acc1[j] = f4axpy(wv1[kk], rk[kk], acc1[j]);
            }
        }
    }

#pragma unroll
    for (int j = 0; j < 4; ++j) {
        int node = nbase + j;
        if (node < n) {
            H8 o = f_to_h8(acc0[j], acc1[j]);
            *(uint4*)((__half*)z + (size_t)node * FO + g * 8) = o.u;
        }
    }

    if (STATS) {
        float4 s0 = f4z(), s1 = f4z(), q0 = f4z(), q1 = f4z();
#pragma unroll
        for (int j = 0; j < 4; ++j) {
            s0.x += acc0[j].x; s0.y += acc0[j].y; s0.z += acc0[j].z; s0.w += acc0[j].w;
            s1.x += acc1[j].x; s1.y += acc1[j].y; s1.z += acc1[j].z; s1.w += acc1[j].w;
            q0.x = fmaf(acc0[j].x, acc0[j].x, q0.x); q0.y = fmaf(acc0[j].y, acc0[j].y, q0.y);
            q0.z = fmaf(acc0[j].z, acc0[j].z, q0.z); q0.w = fmaf(acc0[j].w, acc0[j].w, q0.w);
            q1.x = fmaf(acc1[j].x, acc1[j].x, q1.x); q1.y = fmaf(acc1[j].y, acc1[j].y, q1.y);
            q1.z = fmaf(acc1[j].z, acc1[j].z, q1.z); q1.w = fmaf(acc1[j].w, acc1[j].w, q1.w);
        }
        float* slot = &sred[threadIdx.x * 16];
        *(float4*)(slot + 0) = s0;
        *(float4*)(slot + 4) = s1;
        *(float4*)(slot + 8) = q0;
        *(float4*)(slot + 12) = q1;
        __syncthreads();
        if (threadIdx.x < FO * 2) {
            int c = threadIdx.x % FO;
            int m = threadIdx.x / FO;
            int g2 = c / 8, ci = c % 8;
            float a = 0.f;
            for (int nl2 = 0; nl2 < TPB / GROUPS; ++nl2)
                a += sred[(nl2 * GROUPS + g2) * 16 + m * 8 + ci];
            atomicAdd(&stats[m * FO + c], a);
        }
    }
}

// ---------------- CSR gather (half in/out), optional fused BN-affine+ReLU, optional stats ----

template <int F, bool AFFINE, bool STATS>
__global__ __launch_bounds__(TPB) void k_gather(const int* __restrict__ row_ptr,
                                                const int* __restrict__ csr_src,
                                                const float* __restrict__ dis,
                                                const __half* __restrict__ z,
                                                __half* __restrict__ t,
                                                const float* __restrict__ stats_in,
                                                const float* __restrict__ gg,
                                                const float* __restrict__ be, float inv_n,
                                                float* __restrict__ stats_out, int n) {
    constexpr int GW = (F < 32) ? F : 32;
    constexpr int PARTS = F / GW;
    constexpr int NV = GW / 4;  // float4 accumulators
    constexpr int NL = GW / 8;  // 16B half8 loads
    __shared__ float sred[STATS ? TPB * 16 : 1];
    int tid = blockIdx.x * blockDim.x + threadIdx.x;
    int node = tid / PARTS;
    int part = tid % PARTS;
    bool active = node < n;
    if (!STATS && !active) return;
    const int cbase = part * GW;

    float4 sc[NV], sb[NV];
    if (AFFINE) {
#pragma unroll
        for (int v = 0; v < NV; ++v) {
            float scv[4], sbv[4];
#pragma unroll
            for (int u = 0; u < 4; ++u) {
                int c = cbase + v * 4 + u;
                float mu = stats_in[c] * inv_n;
                float var = stats_in[F + c] * inv_n - mu * mu;
                float s = gg[c] * rsqrtf(var + 1e-5f);
                scv[u] = s;
                sbv[u] = fmaf(-mu, s, be[c]);
            }
            sc[v] = make_float4(scv[0], scv[1], scv[2], scv[3]);
            sb[v] = make_float4(sbv[0], sbv[1], sbv[2], sbv[3]);
        }
    }

    float4 acc[NV];
#pragma unroll
    for (int v = 0; v < NV; ++v) acc[v] = f4z();

    if (active) {
        float dn = dis[node];
        float w0 = dn * dn;
        const uint4* zp = (const uint4*)(z + (size_t)node * F + cbase);
#pragma unroll
        for (int l = 0; l < NL; ++l) {
            H8 hv; hv.u = zp[l];
            float4 a, b;
            h8_to_f(hv, a, b);
            if (AFFINE) { a = f4relu_aff(a, sc[2 * l], sb[2 * l]); b = f4relu_aff(b, sc[2 * l + 1], sb[2 * l + 1]); }
            acc[2 * l] = f4axpy(a, w0, acc[2 * l]);
            acc[2 * l + 1] = f4axpy(b, w0, acc[2 * l + 1]);
        }
        int beg = row_ptr[node], end = row_ptr[node + 1];
        for (int j = beg; j < end; ++j) {
            int s = csr_src[j];
            float w = dn * dis[s];
            const uint4* sp = (const uint4*)(z + (size_t)s * F + cbase);
#pragma unroll
            for (int l = 0; l < NL; ++l) {
                H8 hv; hv.u = sp[l];
                float4 a, b;
                h8_to_f(hv, a, b);
                if (AFFINE) { a = f4relu_aff(a, sc[2 * l], sb[2 * l]); b = f4relu_aff(b, sc[2 * l + 1], sb[2 * l + 1]); }
                acc[2 * l] = f4axpy(a, w, acc[2 * l]);
                acc[2 * l + 1] = f4axpy(b, w, acc[2 * l + 1]);
            }
        }
        uint4* tp = (uint4*)(t + (size_t)node * F + cbase);
#pragma unroll
        for (int l = 0; l < NL; ++l) tp[l] = f_to_h8(acc[2 * l], acc[2 * l + 1]).u;
    }

    if (STATS) {  // only instantiated with F==8 (PARTS==1, NV==2)
        float* slot = &sred[threadIdx.x * 16];
        *(float4*)(slot + 0) = acc[0];
        *(float4*)(slot + 4) = acc[1];
        float4 q0 = make_float4(acc[0].x * acc[0].x, acc[0].y * acc[0].y, acc[0].z * acc[0].z,
                                acc[0].w * acc[0].w);
        float4 q1 = make_float4(acc[1].x * acc[1].x, acc[1].y * acc[1].y, acc[1].z * acc[1].z,
                                acc[1].w * acc[1].w);
        *(float4*)(slot + 8) = q0;
        *(float4*)(slot + 12) = q1;
        __syncthreads();
        if (threadIdx.x < 16) {
            int c = threadIdx.x % 8;
            int m = threadIdx.x / 8;
            float a = 0.f;
            for (int t2 = 0; t2 < TPB; ++t2) a += sred[t2 * 16 + m * 8 + c];
            atomicAdd(&stats_out[m * 8 + c], a);
        }
    }
}

// ---------------- segment multi-aggregation (applies final BN affine, no relu) ----------------

__global__ void k_seg_off(const int* __restrict__ bidx, int n, int* __restrict__ seg_off, int S) {
    int s = blockIdx.x * blockDim.x + threadIdx.x;
    if (s > S) return;
    int lo = 0, hi = n;
    while (lo < hi) {
        int mid = (lo + hi) >> 1;
        if (bidx[mid] < s) lo = mid + 1; else hi = mid;
    }
    seg_off[s] = lo;
}

__global__ __launch_bounds__(TPB) void k_seg_reduce(const __half* __restrict__ z,
                                                    const int* __restrict__ seg_off,
                                                    float* __restrict__ aggin,
                                                    const float* __restrict__ stats,
                                                    const float* __restrict__ gg,
                                                    const float* __restrict__ be, float inv_n) {
    int s = blockIdx.x;
    int start = seg_off[s], end = seg_off[s + 1];
    int c = threadIdx.x & 63;
    float mu = stats[c] * inv_n;
    float var = stats[64 + c] * inv_n - mu * mu;
    float scv = gg[c] * rsqrtf(var + 1e-5f);
    float sbv = fmaf(-mu, scv, be[c]);
    int r0 = start + (threadIdx.x >> 6);
    float sm = 0.f, sm2 = 0.f, mn = INFINITY, mx = -INFINITY;
    for (int r = r0; r < end; r += 4) {
        float v = fmaf(__half2float(z[(size_t)r * 64 + c]), scv, sbv);
        sm += v;
        sm2 = fmaf(v, v, sm2);
        mn = fminf(mn, v);
        mx = fmaxf(mx, v);
    }
    __shared__ float s_sm[TPB], s_sm2[TPB], s_mn[TPB], s_mx[TPB];
    s_sm[threadIdx.x] = sm;
    s_sm2[threadIdx.x] = sm2;
    s_mn[threadIdx.x] = mn;
    s_mx[threadIdx.x] = mx;
    __syncthreads();
    if (threadIdx.x < 64) {
        for (int t = threadIdx.x + 64; t < TPB; t += 64) {
            sm += s_sm[t];
            sm2 += s_sm2[t];
            mn = fminf(mn, s_mn[t]);
            mx = fmaxf(mx, s_mx[t]);
        }
        int count = end - start;
        float cnt = (float)(count > 0 ? count : 1);
        float mean = sm / cnt;
        float var2 = sm2 / cnt - mean * mean;
        if (var2 < 0.f) var2 = 0.f;
        float sd = sqrtf(var2 + 1e-5f);
        if (count <= 0) { mn = 0.f; mx = 0.f; }
        aggin[s * 256 + c] = mean;
        aggin[s * 256 + 64 + c] = mn;
        aggin[s * 256 + 128 + c] = mx;
        aggin[s * 256 + 192 + c] = sd;
    }
}

__global__ __launch_bounds__(64) void k_proj(const float* __restrict__ aggin,
                                             const float* __restrict__ Wp,
                                             const float* __restrict__ bp,
                                             float* __restrict__ proj) {
    __shared__ float sA[256];
    int s = blockIdx.x;
    int j = threadIdx.x;
    for (int k = j; k < 256; k += 64) sA[k] = aggin[s * 256 + k];
    __syncthreads();
    float acc = bp[j];
#pragma unroll 8
    for (int k = 0; k < 256; ++k) acc = fmaf(sA[k], Wp[k * 64 + j], acc);
    proj[s * 64 + j] = acc;
}

__global__ void k_pack(const float* __restrict__ proj, const int* __restrict__ num_sp,
                       float* __restrict__ out, int B, int S) {
    int idx = blockIdx.x * blockDim.x + threadIdx.x;
    int total = B * 64 * 196;
    if (idx >= total) return;
    int ii = idx % 14;
    int jj = (idx / 14) % 14;
    int c = (idx / 196) % 64;
    int b = idx / (196 * 64);
    int p = ii * 14 + jj;
    int off = 0;
    for (int k = 0; k < b; ++k) off += num_sp[k];
    float v = 0.f;
    if (p < num_sp[b]) {
        int s = off + p;
        if (s > S - 1) s = S - 1;
        v = proj[s * 64 + c];
    }
    out[idx] = v;
}

// ---------------- launch ----------------

extern "C" void kernel_launch(void* const* d_in, const int* in_sizes, int n_in,
                              void* d_out, int out_size, void* d_ws, size_t ws_size,
                              hipStream_t stream) {
    const float* x = (const float*)d_in[0];
    const int* ei = (const int*)d_in[1];
    const int* bidx = (const int*)d_in[2];
    const int* num_sp = (const int*)d_in[3];
    const float* Wl[5], * Gl[5], * BEl[5];
    for (int i = 0; i < 5; ++i) {
        Wl[i] = (const float*)d_in[4 + 4 * i];
        // bias skipped: per-channel constant cancels in training-mode BN
        Gl[i] = (const float*)d_in[6 + 4 * i];
        BEl[i] = (const float*)d_in[7 + 4 * i];
    }
    const float* Wp = (const float*)d_in[24];
    const float* bp = (const float*)d_in[25];

    const int n = in_sizes[0] / 24;
    const int E = in_sizes[1] / 2;
    const int B = in_sizes[3];
    const int S = 1200;
    const int* src = ei;
    const int* dst = ei + E;
    const float inv_n = 1.0f / (float)n;
    const int n_scan_blk = (n + SCAN_ELEMS - 1) / SCAN_ELEMS;
    const int nb = (n + (1 << BSH) - 1) >> BSH;  // buckets

    char* w = (char*)d_ws;
    __half* bufZ = (__half*)w;  w += (size_t)n * 64 * 2;
    __half* bufT = (__half*)w;  w += (size_t)n * 64 * 2;
    float* dis = (float*)w;     w += (size_t)n * 4;
    int* deg = (int*)w;         w += (size_t)n * 4;
    int* row_ptr = (int*)w;     w += (size_t)(n + 64) * 4;
    int* cursor = (int*)w;      w += (size_t)n * 4;
    int* csr_src = (int*)w;     w += (size_t)E * 4;
    int2* bin = (int2*)w;       w += (size_t)E * 8;
    int* bcur = (int*)w;        w += (size_t)(nb + 64) * 4;
    int* blk_sum = (int*)w;     w += (size_t)n_scan_blk * 4 + 256;
    int* blk_off = (int*)w;     w += (size_t)n_scan_blk * 4 + 256;
    float* stats_all = (float*)w; w += 5 * 128 * 4;
    int* seg_off = (int*)w;     w += 8192;
    float* aggin = (float*)w;   w += (size_t)S * 256 * 4;
    float* proj = (float*)w;    w += (size_t)S * 64 * 4;
    float* st0 = stats_all;        // 2*8
    float* st1 = stats_all + 128;  // 2*16
    float* st2 = stats_all + 256;  // 2*32
    float* st3 = stats_all + 384;  // 2*64
    float* st4 = stats_all + 512;  // 2*64

    // ---- CSR build ----
    hipMemsetAsync(deg, 0, (size_t)n * 4, stream);
    hipMemsetAsync(stats_all, 0, 5 * 128 * 4, stream);
    k_hist<<<(E + TPB - 1) / TPB, TPB, 0, stream>>>(dst, deg, E);
    k_dis<<<(n + TPB - 1) / TPB, TPB, 0, stream>>>(deg, dis, n);
    k_scan1<<<n_scan_blk, 256, 0, stream>>>(deg, n, row_ptr, blk_sum);
    k_scan2<<<1, 64, 0, stream>>>(blk_sum, blk_off, n_scan_blk);
    k_scan3<<<(n + 1 + TPB - 1) / TPB, TPB, 0, stream>>>(row_ptr, blk_off, n, E, cursor);
    k_bucket_init<<<(nb + TPB - 1) / TPB, TPB, 0, stream>>>(row_ptr, bcur, n, nb);
    k_partA<<<(E + 8191) / 8192, 256, 0, stream>>>(src, dst, E, bcur, bin, nb);
    k_partB<<<(E + TPB - 1) / TPB, TPB, 0, stream>>>(bin, cursor, csr_src, E);

    // ---- Layer 1: m = x@W1 ; z1 = Agg(m) with fused stats ----
    k_mm<24, 8, false, true><<<(n + 1023) / 1024, TPB, 0, stream>>>(x, Wl[0], bufT, nullptr, n);
    k_gather<8, false, true><<<(n + TPB - 1) / TPB, TPB, 0, stream>>>(
        row_ptr, csr_src, dis, bufT, bufZ, nullptr, nullptr, nullptr, inv_n, st0, n);

    // ---- Layers 2-5: t = Agg(relu(bn(z))) ; z = t@W (stats fused) ----
    k_gather<8, true, false><<<(n + TPB - 1) / TPB, TPB, 0, stream>>>(
        row_ptr, csr_src, dis, bufZ, bufT, st0, Gl[0], BEl[0], inv_n, nullptr, n);
    k_mm<8, 16, true, false><<<(n + 511) / 512, TPB, 0, stream>>>(bufT, Wl[1], bufZ, st1, n);

    k_gather<16, true, false><<<(n + TPB - 1) / TPB, TPB, 0, stream>>>(
        row_ptr, csr_src, dis, bufZ, bufT, st1, Gl[1], BEl[1], inv_n, nullptr, n);
    k_mm<16, 32, true, false><<<(n + 255) / 256, TPB, 0, stream>>>(bufT, Wl[2], bufZ, st2, n);

    k_gather<32, true, false><<<(n + TPB - 1) / TPB, TPB, 0, stream>>>(
        row_ptr, csr_src, dis, bufZ, bufT, st2, Gl[2], BEl[2], inv_n, nullptr, n);
    k_mm<32, 64, true, false><<<(n + 127) / 128, TPB, 0, stream>>>(bufT, Wl[3], bufZ, st3, n);

    k_gather<64, true, false><<<(2 * n + TPB - 1) / TPB, TPB, 0, stream>>>(
        row_ptr, csr_src, dis, bufZ, bufT, st3, Gl[3], BEl[3], inv_n, nullptr, n);
    k_mm<64, 64, true, false><<<(n + 127) / 128, TPB, 0, stream>>>(bufT, Wl[4], bufZ, st4, n);

    // ---- tail ----
    k_seg_off<<<(S + 1 + TPB - 1) / TPB, TPB, 0, stream>>>(bidx, n, seg_off, S);
    k_seg_reduce<<<S, TPB, 0, stream>>>(bufZ, seg_off, aggin, st4, Gl[4], BEl[4], inv_n);
    k_proj<<<S, 64, 0, stream>>>(aggin, Wp, bp, proj);
    int total_out = B * 64 * 196;
    k_pack<<<(total_out + TPB - 1) / TPB, TPB, 0, stream>>>(proj, num_sp, (float*)d_out, B, S);
}

// Round 5
// 1124.300 us; speedup vs baseline: 8.2916x; 1.1873x over previous
//
#include <hip/hip_runtime.h>
#include <hip/hip_fp16.h>

#define TPB 256
#define BSH 10        // 1024 nodes per bucket
#define NBMAX 1024    // max buckets supported by LDS hist
#define CAP 12288     // LDS staging capacity per bucket (edges)

// ---------------- half helpers ----------------

union H8 { uint4 u; __half2 h[4]; };
union H4 { uint2 u; __half2 h[2]; };

__device__ inline void h8_to_f(const H8 v, float4& a, float4& b) {
    float2 f0 = __half22float2(v.h[0]);
    float2 f1 = __half22float2(v.h[1]);
    float2 f2 = __half22float2(v.h[2]);
    float2 f3 = __half22float2(v.h[3]);
    a = make_float4(f0.x, f0.y, f1.x, f1.y);
    b = make_float4(f2.x, f2.y, f3.x, f3.y);
}
__device__ inline H8 f_to_h8(float4 a, float4 b) {
    H8 r;
    r.h[0] = __floats2half2_rn(a.x, a.y);
    r.h[1] = __floats2half2_rn(a.z, a.w);
    r.h[2] = __floats2half2_rn(b.x, b.y);
    r.h[3] = __floats2half2_rn(b.z, b.w);
    return r;
}
__device__ inline float4 f4z() { return make_float4(0.f, 0.f, 0.f, 0.f); }
__device__ inline float4 f4axpy(float4 a, float s, float4 c) {
    return make_float4(fmaf(a.x, s, c.x), fmaf(a.y, s, c.y), fmaf(a.z, s, c.z), fmaf(a.w, s, c.w));
}
__device__ inline float4 f4relu_aff(float4 h, float4 sc, float4 sb) {
    return make_float4(fmaxf(fmaf(h.x, sc.x, sb.x), 0.f), fmaxf(fmaf(h.y, sc.y, sb.y), 0.f),
                       fmaxf(fmaf(h.z, sc.z, sb.z), 0.f), fmaxf(fmaf(h.w, sc.w, sb.w), 0.f));
}

// ---------------- CSR build, bucket-local ----------------

// per-block LDS histogram over buckets -> global bucket counts
__global__ __launch_bounds__(256) void k_bcount(const int* __restrict__ dst, int E,
                                                int* __restrict__ bcount, int nb) {
    __shared__ int hist[NBMAX];
    for (int i = threadIdx.x; i < nb; i += 256) hist[i] = 0;
    __syncthreads();
    const int e0 = blockIdx.x * 8192;
#pragma unroll 4
    for (int k = 0; k < 32; ++k) {
        int e = e0 + k * 256 + threadIdx.x;
        if (e < E) atomicAdd(&hist[dst[e] >> BSH], 1);
    }
    __syncthreads();
    for (int i = threadIdx.x; i < nb; i += 256) {
        int h = hist[i];
        if (h) atomicAdd(&bcount[i], h);
    }
}

// single-block scan over nb buckets -> bbase (excl prefix, bbase[nb]=E), bcur copy
__global__ void k_bscan(const int* __restrict__ bcount, int* __restrict__ bbase,
                        int* __restrict__ bcur, int nb, int E, int* __restrict__ row_ptr,
                        int n) {
    if (threadIdx.x == 0 && blockIdx.x == 0) {
        int run = 0;
        for (int i = 0; i < nb; ++i) {
            bbase[i] = run;
            bcur[i] = run;
            run += bcount[i];
        }
        bbase[nb] = E;
        row_ptr[n] = E;
    }
}

// pass A: bin (src,dst) pairs into final per-bucket CSR windows (unordered within bucket)
__global__ __launch_bounds__(256) void k_partA(const int* __restrict__ src,
                                               const int* __restrict__ dst, int E,
                                               int* __restrict__ bcur, int2* __restrict__ bin,
                                               int nb) {
    __shared__ int hist[NBMAX];
    __shared__ int base[NBMAX];
    for (int i = threadIdx.x; i < nb; i += 256) hist[i] = 0;
    __syncthreads();
    const int e0 = blockIdx.x * 8192;
#pragma unroll 4
    for (int k = 0; k < 32; ++k) {
        int e = e0 + k * 256 + threadIdx.x;
        if (e < E) atomicAdd(&hist[dst[e] >> BSH], 1);
    }
    __syncthreads();
    for (int i = threadIdx.x; i < nb; i += 256) {
        int h = hist[i];
        base[i] = h ? atomicAdd(&bcur[i], h) : 0;
        hist[i] = 0;
    }
    __syncthreads();
#pragma unroll 4
    for (int k = 0; k < 32; ++k) {
        int e = e0 + k * 256 + threadIdx.x;
        if (e < E) {
            int d = dst[e];
            int b = d >> BSH;
            int off = atomicAdd(&hist[b], 1);
            bin[base[b] + off] = make_int2(src[e], d);
        }
    }
}

// pass B: block per bucket. LDS deg-hist -> LDS scan -> row_ptr/dis slices (coalesced)
// -> LDS-cursor scatter into LDS stage -> coalesced dump to csr_src.
__global__ __launch_bounds__(256) void k_csr_bucket(const int2* __restrict__ bin,
                                                    const int* __restrict__ bbase,
                                                    int* __restrict__ row_ptr,
                                                    float* __restrict__ dis,
                                                    int* __restrict__ csr_src, int n) {
    __shared__ int ldeg[1024];
    __shared__ int lcur[1024];
    __shared__ int ts[256];
    __shared__ int stage[CAP];
    const int b = blockIdx.x;
    const int node0 = b << BSH;
    const int nodes = min(1024, n - node0);
    const int ebeg = bbase[b], eend = bbase[b + 1];
    const int cnt = eend - ebeg;

    for (int i = threadIdx.x; i < 1024; i += 256) ldeg[i] = 0;
    __syncthreads();
    for (int e = ebeg + threadIdx.x; e < eend; e += 256)
        atomicAdd(&ldeg[bin[e].y & 1023], 1);
    __syncthreads();

    // exclusive scan over 1024 (4 per thread)
    const int b4 = threadIdx.x * 4;
    int v0 = ldeg[b4], v1 = ldeg[b4 + 1], v2 = ldeg[b4 + 2], v3 = ldeg[b4 + 3];
    ts[threadIdx.x] = v0 + v1 + v2 + v3;
    __syncthreads();
    for (int off = 1; off < 256; off <<= 1) {
        int t = (threadIdx.x >= off) ? ts[threadIdx.x - off] : 0;
        __syncthreads();
        ts[threadIdx.x] += t;
        __syncthreads();
    }
    int o0 = (threadIdx.x == 0) ? 0 : ts[threadIdx.x - 1];
    int o1 = o0 + v0, o2 = o1 + v1, o3 = o2 + v2;
    lcur[b4] = o0; lcur[b4 + 1] = o1; lcur[b4 + 2] = o2; lcur[b4 + 3] = o3;
    // row_ptr / dis slices (coalesced-ish, 4 consecutive per thread)
    if (b4 + 3 < nodes) {
        row_ptr[node0 + b4] = ebeg + o0;
        row_ptr[node0 + b4 + 1] = ebeg + o1;
        row_ptr[node0 + b4 + 2] = ebeg + o2;
        row_ptr[node0 + b4 + 3] = ebeg + o3;
        dis[node0 + b4] = rsqrtf((float)(v0 + 1));
        dis[node0 + b4 + 1] = rsqrtf((float)(v1 + 1));
        dis[node0 + b4 + 2] = rsqrtf((float)(v2 + 1));
        dis[node0 + b4 + 3] = rsqrtf((float)(v3 + 1));
    } else {
        int vv[4] = {v0, v1, v2, v3};
        int oo[4] = {o0, o1, o2, o3};
        for (int u = 0; u < 4; ++u) {
            if (b4 + u < nodes) {
                row_ptr[node0 + b4 + u] = ebeg + oo[u];
                dis[node0 + b4 + u] = rsqrtf((float)(vv[u] + 1));
            }
        }
    }
    __syncthreads();

    // scatter into stage via LDS cursors
    for (int e = ebeg + threadIdx.x; e < eend; e += 256) {
        int2 p = bin[e];
        int pos = atomicAdd(&lcur[p.y & 1023], 1);
        if (pos < CAP) stage[pos] = p.x;
        else csr_src[ebeg + pos] = p.x;  // overflow path (cnt > CAP), rare
    }
    __syncthreads();
    int m = cnt < CAP ? cnt : CAP;
    for (int i = threadIdx.x; i < m; i += 256) csr_src[ebeg + i] = stage[i];
}

// ---------------- register-tiled matmul z = t @ W (half out), optional fused BN stats -----

template <int FI, int FO, bool STATS, bool IN_F32>
__global__ __launch_bounds__(TPB) void k_mm(const void* __restrict__ tin,
                                            const float* __restrict__ W, __half* __restrict__ z,
                                            float* __restrict__ stats, int n) {
    constexpr int GROUPS = FO / 8;
    constexpr int NPB = (TPB / GROUPS) * 4;
    __shared__ float sW[FI * FO];
    __shared__ float sred[STATS ? TPB * 16 : 1];
    for (int i = threadIdx.x; i < FI * FO; i += TPB) sW[i] = W[i];
    __syncthreads();

    const int g = threadIdx.x % GROUPS;
    const int nl = threadIdx.x / GROUPS;
    const int nbase = blockIdx.x * NPB + nl * 4;

    float4 acc0[4], acc1[4];
#pragma unroll
    for (int j = 0; j < 4; ++j) { acc0[j] = f4z(); acc1[j] = f4z(); }

    for (int k = 0; k < FI; k += 4) {
        float4 wv0[4], wv1[4];
#pragma unroll
        for (int kk = 0; kk < 4; ++kk) {
            wv0[kk] = *(const float4*)&sW[(k + kk) * FO + g * 8];
            wv1[kk] = *(const float4*)&sW[(k + kk) * FO + g * 8 + 4];
        }
#pragma unroll
        for (int j = 0; j < 4; ++j) {
            int node = nbase + j;
            float rk[4] = {0.f, 0.f, 0.f, 0.f};
            if (node < n) {
                if (IN_F32) {
                    float4 rv = *(const float4*)((const float*)tin + (size_t)node * FI + k);
                    rk[0] = rv.x; rk[1] = rv.y; rk[2] = rv.z; rk[3] = rv.w;
                } else {
                    H4 hv;
                    hv.u = *(const uint2*)((const __half*)tin + (size_t)node * FI + k);
                    float2 f0 = __half22float2(hv.h[0]);
                    float2 f1 = __half22float2(hv.h[1]);
                    rk[0] = f0.x; rk[1] = f0.y; rk[2] = f1.x; rk[3] = f1.y;
                }
            }
#pragma unroll
            for (int kk = 0; kk < 4; ++kk) {
                acc0[j] = f4axpy(wv0[kk], rk[kk], acc0[j]);
                acc1[j] = f4axpy(wv1[kk], rk[kk], acc1[j]);
            }
        }
    }

#pragma unroll
    for (int j = 0; j < 4; ++j) {
        int node = nbase + j;
        if (node < n) {
            H8 o = f_to_h8(acc0[j], acc1[j]);
            *(uint4*)((__half*)z + (size_t)node * FO + g * 8) = o.u;
        }
    }

    if (STATS) {
        float4 s0 = f4z(), s1 = f4z(), q0 = f4z(), q1 = f4z();
#pragma unroll
        for (int j = 0; j < 4; ++j) {
            s0.x += acc0[j].x; s0.y += acc0[j].y; s0.z += acc0[j].z; s0.w += acc0[j].w;
            s1.x += acc1[j].x; s1.y += acc1[j].y; s1.z += acc1[j].z; s1.w += acc1[j].w;
            q0.x = fmaf(acc0[j].x, acc0[j].x, q0.x); q0.y = fmaf(acc0[j].y, acc0[j].y, q0.y);
            q0.z = fmaf(acc0[j].z, acc0[j].z, q0.z); q0.w = fmaf(acc0[j].w, acc0[j].w, q0.w);
            q1.x = fmaf(acc1[j].x, acc1[j].x, q1.x); q1.y = fmaf(acc1[j].y, acc1[j].y, q1.y);
            q1.z = fmaf(acc1[j].z, acc1[j].z, q1.z); q1.w = fmaf(acc1[j].w, acc1[j].w, q1.w);
        }
        float* slot = &sred[threadIdx.x * 16];
        *(float4*)(slot + 0) = s0;
        *(float4*)(slot + 4) = s1;
        *(float4*)(slot + 8) = q0;
        *(float4*)(slot + 12) = q1;
        __syncthreads();
        if (threadIdx.x < FO * 2) {
            int c = threadIdx.x % FO;
            int m = threadIdx.x / FO;
            int g2 = c / 8, ci = c % 8;
            float a = 0.f;
            for (int nl2 = 0; nl2 < TPB / GROUPS; ++nl2)
                a += sred[(nl2 * GROUPS + g2) * 16 + m * 8 + ci];
            atomicAdd(&stats[m * FO + c], a);
        }
    }
}

// ---------------- CSR gather (half in/out), optional fused BN-affine+ReLU, optional stats ----

template <int F, bool AFFINE, bool STATS>
__global__ __launch_bounds__(TPB) void k_gather(const int* __restrict__ row_ptr,
                                                const int* __restrict__ csr_src,
                                                const float* __restrict__ dis,
                                                const __half* __restrict__ z,
                                                __half* __restrict__ t,
                                                const float* __restrict__ stats_in,
                                                const float* __restrict__ gg,
                                                const float* __restrict__ be, float inv_n,
                                                float* __restrict__ stats_out, int n) {
    constexpr int GW = (F < 32) ? F : 32;
    constexpr int PARTS = F / GW;
    constexpr int NV = GW / 4;
    constexpr int NL = GW / 8;
    __shared__ float sred[STATS ? TPB * 16 : 1];
    int tid = blockIdx.x * blockDim.x + threadIdx.x;
    int node = tid / PARTS;
    int part = tid % PARTS;
    bool active = node < n;
    if (!STATS && !active) return;
    const int cbase = part * GW;

    float4 sc[NV], sb[NV];
    if (AFFINE) {
#pragma unroll
        for (int v = 0; v < NV; ++v) {
            float scv[4], sbv[4];
#pragma unroll
            for (int u = 0; u < 4; ++u) {
                int c = cbase + v * 4 + u;
                float mu = stats_in[c] * inv_n;
                float var = stats_in[F + c] * inv_n - mu * mu;
                float s = gg[c] * rsqrtf(var + 1e-5f);
                scv[u] = s;
                sbv[u] = fmaf(-mu, s, be[c]);
            }
            sc[v] = make_float4(scv[0], scv[1], scv[2], scv[3]);
            sb[v] = make_float4(sbv[0], sbv[1], sbv[2], sbv[3]);
        }
    }

    float4 acc[NV];
#pragma unroll
    for (int v = 0; v < NV; ++v) acc[v] = f4z();

    if (active) {
        float dn = dis[node];
        float w0 = dn * dn;
        const uint4* zp = (const uint4*)(z + (size_t)node * F + cbase);
#pragma unroll
        for (int l = 0; l < NL; ++l) {
            H8 hv; hv.u = zp[l];
            float4 a, b;
            h8_to_f(hv, a, b);
            if (AFFINE) { a = f4relu_aff(a, sc[2 * l], sb[2 * l]); b = f4relu_aff(b, sc[2 * l + 1], sb[2 * l + 1]); }
            acc[2 * l] = f4axpy(a, w0, acc[2 * l]);
            acc[2 * l + 1] = f4axpy(b, w0, acc[2 * l + 1]);
        }
        int beg = row_ptr[node], end = row_ptr[node + 1];
        for (int j = beg; j < end; ++j) {
            int s = csr_src[j];
            float w = dn * dis[s];
            const uint4* sp = (const uint4*)(z + (size_t)s * F + cbase);
#pragma unroll
            for (int l = 0; l < NL; ++l) {
                H8 hv; hv.u = sp[l];
                float4 a, b;
                h8_to_f(hv, a, b);
                if (AFFINE) { a = f4relu_aff(a, sc[2 * l], sb[2 * l]); b = f4relu_aff(b, sc[2 * l + 1], sb[2 * l + 1]); }
                acc[2 * l] = f4axpy(a, w, acc[2 * l]);
                acc[2 * l + 1] = f4axpy(b, w, acc[2 * l + 1]);
            }
        }
        uint4* tp = (uint4*)(t + (size_t)node * F + cbase);
#pragma unroll
        for (int l = 0; l < NL; ++l) tp[l] = f_to_h8(acc[2 * l], acc[2 * l + 1]).u;
    }

    if (STATS) {  // only instantiated with F==8 (PARTS==1, NV==2)
        float* slot = &sred[threadIdx.x * 16];
        *(float4*)(slot + 0) = acc[0];
        *(float4*)(slot + 4) = acc[1];
        float4 q0 = make_float4(acc[0].x * acc[0].x, acc[0].y * acc[0].y, acc[0].z * acc[0].z,
                                acc[0].w * acc[0].w);
        float4 q1 = make_float4(acc[1].x * acc[1].x, acc[1].y * acc[1].y, acc[1].z * acc[1].z,
                                acc[1].w * acc[1].w);
        *(float4*)(slot + 8) = q0;
        *(float4*)(slot + 12) = q1;
        __syncthreads();
        if (threadIdx.x < 16) {
            int c = threadIdx.x % 8;
            int m = threadIdx.x / 8;
            float a = 0.f;
            for (int t2 = 0; t2 < TPB; ++t2) a += sred[t2 * 16 + m * 8 + c];
            atomicAdd(&stats_out[m * 8 + c], a);
        }
    }
}

// ---------------- segment multi-aggregation (applies final BN affine, no relu) ----------------

__global__ void k_seg_off(const int* __restrict__ bidx, int n, int* __restrict__ seg_off, int S) {
    int s = blockIdx.x * blockDim.x + threadIdx.x;
    if (s > S) return;
    int lo = 0, hi = n;
    while (lo < hi) {
        int mid = (lo + hi) >> 1;
        if (bidx[mid] < s) lo = mid + 1; else hi = mid;
    }
    seg_off[s] = lo;
}

__global__ __launch_bounds__(TPB) void k_seg_reduce(const __half* __restrict__ z,
                                                    const int* __restrict__ seg_off,
                                                    float* __restrict__ aggin,
                                                    const float* __restrict__ stats,
                                                    const float* __restrict__ gg,
                                                    const float* __restrict__ be, float inv_n) {
    int s = blockIdx.x;
    int start = seg_off[s], end = seg_off[s + 1];
    int c = threadIdx.x & 63;
    float mu = stats[c] * inv_n;
    float var = stats[64 + c] * inv_n - mu * mu;
    float scv = gg[c] * rsqrtf(var + 1e-5f);
    float sbv = fmaf(-mu, scv, be[c]);
    int r0 = start + (threadIdx.x >> 6);
    float sm = 0.f, sm2 = 0.f, mn = INFINITY, mx = -INFINITY;
    for (int r = r0; r < end; r += 4) {
        float v = fmaf(__half2float(z[(size_t)r * 64 + c]), scv, sbv);
        sm += v;
        sm2 = fmaf(v, v, sm2);
        mn = fminf(mn, v);
        mx = fmaxf(mx, v);
    }
    __shared__ float s_sm[TPB], s_sm2[TPB], s_mn[TPB], s_mx[TPB];
    s_sm[threadIdx.x] = sm;
    s_sm2[threadIdx.x] = sm2;
    s_mn[threadIdx.x] = mn;
    s_mx[threadIdx.x] = mx;
    __syncthreads();
    if (threadIdx.x < 64) {
        for (int t = threadIdx.x + 64; t < TPB; t += 64) {
            sm += s_sm[t];
            sm2 += s_sm2[t];
            mn = fminf(mn, s_mn[t]);
            mx = fmaxf(mx, s_mx[t]);
        }
        int count = end - start;
        float cnt = (float)(count > 0 ? count : 1);
        float mean = sm / cnt;
        float var2 = sm2 / cnt - mean * mean;
        if (var2 < 0.f) var2 = 0.f;
        float sd = sqrtf(var2 + 1e-5f);
        if (count <= 0) { mn = 0.f; mx = 0.f; }
        aggin[s * 256 + c] = mean;
        aggin[s * 256 + 64 + c] = mn;
        aggin[s * 256 + 128 + c] = mx;
        aggin[s * 256 + 192 + c] = sd;
    }
}

__global__ __launch_bounds__(64) void k_proj(const float* __restrict__ aggin,
                                             const float* __restrict__ Wp,
                                             const float* __restrict__ bp,
                                             float* __restrict__ proj) {
    __shared__ float sA[256];
    int s = blockIdx.x;
    int j = threadIdx.x;
    for (int k = j; k < 256; k += 64) sA[k] = aggin[s * 256 + k];
    __syncthreads();
    float acc = bp[j];
#pragma unroll 8
    for (int k = 0; k < 256; ++k) acc = fmaf(sA[k], Wp[k * 64 + j], acc);
    proj[s * 64 + j] = acc;
}

__global__ void k_pack(const float* __restrict__ proj, const int* __restrict__ num_sp,
                       float* __restrict__ out, int B, int S) {
    int idx = blockIdx.x * blockDim.x + threadIdx.x;
    int total = B * 64 * 196;
    if (idx >= total) return;
    int ii = idx % 14;
    int jj = (idx / 14) % 14;
    int c = (idx / 196) % 64;
    int b = idx / (196 * 64);
    int p = ii * 14 + jj;
    int off = 0;
    for (int k = 0; k < b; ++k) off += num_sp[k];
    float v = 0.f;
    if (p < num_sp[b]) {
        int s = off + p;
        if (s > S - 1) s = S - 1;
        v = proj[s * 64 + c];
    }
    out[idx] = v;
}

// ---------------- launch ----------------

extern "C" void kernel_launch(void* const* d_in, const int* in_sizes, int n_in,
                              void* d_out, int out_size, void* d_ws, size_t ws_size,
                              hipStream_t stream) {
    const float* x = (const float*)d_in[0];
    const int* ei = (const int*)d_in[1];
    const int* bidx = (const int*)d_in[2];
    const int* num_sp = (const int*)d_in[3];
    const float* Wl[5], * Gl[5], * BEl[5];
    for (int i = 0; i < 5; ++i) {
        Wl[i] = (const float*)d_in[4 + 4 * i];
        // bias skipped: per-channel constant cancels in training-mode BN
        Gl[i] = (const float*)d_in[6 + 4 * i];
        BEl[i] = (const float*)d_in[7 + 4 * i];
    }
    const float* Wp = (const float*)d_in[24];
    const float* bp = (const float*)d_in[25];

    const int n = in_sizes[0] / 24;
    const int E = in_sizes[1] / 2;
    const int B = in_sizes[3];
    const int S = 1200;
    const int* src = ei;
    const int* dst = ei + E;
    const float inv_n = 1.0f / (float)n;
    const int nb = (n + (1 << BSH) - 1) >> BSH;

    char* w = (char*)d_ws;
    __half* bufZ = (__half*)w;  w += (size_t)n * 64 * 2;
    __half* bufT = (__half*)w;  w += (size_t)n * 64 * 2;
    float* dis = (float*)w;     w += (size_t)n * 4;
    int* row_ptr = (int*)w;     w += (size_t)(n + 64) * 4;
    int* csr_src = (int*)w;     w += (size_t)E * 4;
    int2* bin = (int2*)w;       w += (size_t)E * 8;
    int* bcount = (int*)w;      w += (size_t)(nb + 64) * 4;
    int* bbase = (int*)w;       w += (size_t)(nb + 64) * 4;
    int* bcur = (int*)w;        w += (size_t)(nb + 64) * 4;
    float* stats_all = (float*)w; w += 5 * 128 * 4;
    int* seg_off = (int*)w;     w += 8192;
    float* aggin = (float*)w;   w += (size_t)S * 256 * 4;
    float* proj = (float*)w;    w += (size_t)S * 64 * 4;
    float* st0 = stats_all;
    float* st1 = stats_all + 128;
    float* st2 = stats_all + 256;
    float* st3 = stats_all + 384;
    float* st4 = stats_all + 512;

    // ---- CSR build (bucket-local) ----
    hipMemsetAsync(bcount, 0, (size_t)nb * 4, stream);
    hipMemsetAsync(stats_all, 0, 5 * 128 * 4, stream);
    k_bcount<<<(E + 8191) / 8192, 256, 0, stream>>>(dst, E, bcount, nb);
    k_bscan<<<1, 64, 0, stream>>>(bcount, bbase, bcur, nb, E, row_ptr, n);
    k_partA<<<(E + 8191) / 8192, 256, 0, stream>>>(src, dst, E, bcur, bin, nb);
    k_csr_bucket<<<nb, 256, 0, stream>>>(bin, bbase, row_ptr, dis, csr_src, n);

    // ---- Layer 1: m = x@W1 ; z1 = Agg(m) with fused stats ----
    k_mm<24, 8, false, true><<<(n + 1023) / 1024, TPB, 0, stream>>>(x, Wl[0], bufT, nullptr, n);
    k_gather<8, false, true><<<(n + TPB - 1) / TPB, TPB, 0, stream>>>(
        row_ptr, csr_src, dis, bufT, bufZ, nullptr, nullptr, nullptr, inv_n, st0, n);

    // ---- Layers 2-5: t = Agg(relu(bn(z))) ; z = t@W (stats fused) ----
    k_gather<8, true, false><<<(n + TPB - 1) / TPB, TPB, 0, stream>>>(
        row_ptr, csr_src, dis, bufZ, bufT, st0, Gl[0], BEl[0], inv_n, nullptr, n);
    k_mm<8, 16, true, false><<<(n + 511) / 512, TPB, 0, stream>>>(bufT, Wl[1], bufZ, st1, n);

    k_gather<16, true, false><<<(n + TPB - 1) / TPB, TPB, 0, stream>>>(
        row_ptr, csr_src, dis, bufZ, bufT, st1, Gl[1], BEl[1], inv_n, nullptr, n);
    k_mm<16, 32, true, false><<<(n + 255) / 256, TPB, 0, stream>>>(bufT, Wl[2], bufZ, st2, n);

    k_gather<32, true, false><<<(n + TPB - 1) / TPB, TPB, 0, stream>>>(
        row_ptr, csr_src, dis, bufZ, bufT, st2, Gl[2], BEl[2], inv_n, nullptr, n);
    k_mm<32, 64, true, false><<<(n + 127) / 128, TPB, 0, stream>>>(bufT, Wl[3], bufZ, st3, n);

    k_gather<64, true, false><<<(2 * n + TPB - 1) / TPB, TPB, 0, stream>>>(
        row_ptr, csr_src, dis, bufZ, bufT, st3, Gl[3], BEl[3], inv_n, nullptr, n);
    k_mm<64, 64, true, false><<<(n + 127) / 128, TPB, 0, stream>>>(bufT, Wl[4], bufZ, st4, n);

    // ---- tail ----
    k_seg_off<<<(S + 1 + TPB - 1) / TPB, TPB, 0, stream>>>(bidx, n, seg_off, S);
    k_seg_reduce<<<S, TPB, 0, stream>>>(bufZ, seg_off, aggin, st4, Gl[4], BEl[4], inv_n);
    k_proj<<<S, 64, 0, stream>>>(aggin, Wp, bp, proj);
    int total_out = B * 64 * 196;
    k_pack<<<(total_out + TPB - 1) / TPB, TPB, 0, stream>>>(proj, num_sp, (float*)d_out, B, S);
}